// Round 1
// baseline (6882.028 us; speedup 1.0000x reference)
//
#include <hip/hip_runtime.h>
#include <math.h>

#define CDIV(a,b) (((a)+(b)-1)/(b))

// ---------------------------------------------------------------- utils
__global__ void zero_f32(float* __restrict__ p, int n) {
    int i = blockIdx.x * 256 + threadIdx.x;
    if (i < n) p[i] = 0.f;
}
__global__ void init_att_k(float* __restrict__ m, float* __restrict__ s, int n) {
    int i = blockIdx.x * 256 + threadIdx.x;
    if (i < n) { m[i] = -INFINITY; s[i] = 0.f; }
}
__global__ void init_score_k(float* __restrict__ sc, const float* __restrict__ b, int n) {
    int i = blockIdx.x * 256 + threadIdx.x;
    if (i < n) sc[i] = b[0];
}

// ---------------------------------------------------------------- GEMM
// C[M,Nc] = act( [A1|A2][M,K] @ W[Nc,K]^T + bias ), A1 has K1 cols (row-stride K1),
// A2 covers k in [K1,K) with row-stride ldA2. K % 16 == 0, K1 % 16 == 0, Nc % 64 == 0.
__global__ __launch_bounds__(256)
void gemm_k(const float* __restrict__ A1, int K1,
            const float* __restrict__ A2, int ldA2,
            const float* __restrict__ W, const float* __restrict__ bias,
            float* __restrict__ C, int M, int Nc, int K, int relu)
{
    __shared__ __align__(16) float As[16][68];
    __shared__ __align__(16) float Bs[16][68];
    int tid = threadIdx.x;
    int bm = blockIdx.x * 64;
    int bn = blockIdx.y * 64;
    int tx = tid & 15, ty = tid >> 4;
    int lrow = tid >> 2;
    int lk4 = (tid & 3) * 4;
    float acc[4][4] = {};
    for (int kb = 0; kb < K; kb += 16) {
        int kg = kb + lk4;
        float4 va = make_float4(0.f, 0.f, 0.f, 0.f);
        int m = bm + lrow;
        if (m < M) {
            if (kg < K1) va = *(const float4*)(A1 + (size_t)m * K1 + kg);
            else         va = *(const float4*)(A2 + (size_t)m * ldA2 + (kg - K1));
        }
        As[lk4+0][lrow] = va.x; As[lk4+1][lrow] = va.y;
        As[lk4+2][lrow] = va.z; As[lk4+3][lrow] = va.w;
        float4 vb = *(const float4*)(W + (size_t)(bn + lrow) * K + kg);
        Bs[lk4+0][lrow] = vb.x; Bs[lk4+1][lrow] = vb.y;
        Bs[lk4+2][lrow] = vb.z; Bs[lk4+3][lrow] = vb.w;
        __syncthreads();
        #pragma unroll
        for (int kk = 0; kk < 16; ++kk) {
            float4 a4 = *(float4*)&As[kk][ty*4];
            float4 b4 = *(float4*)&Bs[kk][tx*4];
            float a[4] = {a4.x, a4.y, a4.z, a4.w};
            float b[4] = {b4.x, b4.y, b4.z, b4.w};
            #pragma unroll
            for (int i = 0; i < 4; ++i)
                #pragma unroll
                for (int j = 0; j < 4; ++j)
                    acc[i][j] = fmaf(a[i], b[j], acc[i][j]);
        }
        __syncthreads();
    }
    float4 bb = make_float4(0.f, 0.f, 0.f, 0.f);
    if (bias) bb = *(const float4*)(bias + bn + tx*4);
    #pragma unroll
    for (int i = 0; i < 4; ++i) {
        int m = bm + ty*4 + i;
        if (m >= M) continue;
        float4 v = make_float4(acc[i][0]+bb.x, acc[i][1]+bb.y, acc[i][2]+bb.z, acc[i][3]+bb.w);
        if (relu) { v.x=fmaxf(v.x,0.f); v.y=fmaxf(v.y,0.f); v.z=fmaxf(v.z,0.f); v.w=fmaxf(v.w,0.f); }
        *(float4*)(C + (size_t)m * Nc + bn + tx*4) = v;
    }
}

// ---------------------------------------------------------------- GAT pieces
__global__ void att_sums_k(const float* __restrict__ xp, const float* __restrict__ asrc,
                           const float* __restrict__ adst, float* __restrict__ es,
                           float* __restrict__ ed, int N_) {
    int i = blockIdx.x * 256 + threadIdx.x;
    if (i >= 2 * N_) return;
    int n = i >> 1, h = i & 1;
    const float* row = xp + (size_t)n * 128 + h * 64;
    const float* ws = asrc + h * 64;
    const float* wd = adst + h * 64;
    float s = 0.f, d = 0.f;
    for (int c = 0; c < 64; c += 4) {
        float4 v = *(const float4*)(row + c);
        float4 a = *(const float4*)(ws + c);
        float4 b = *(const float4*)(wd + c);
        s += v.x*a.x + v.y*a.y + v.z*a.z + v.w*a.w;
        d += v.x*b.x + v.y*b.y + v.z*b.z + v.w*b.w;
    }
    es[i] = s; ed[i] = d;
}

__global__ void edge_logit_k(const int* __restrict__ ei, int E, int ET,
                             const float* __restrict__ es, const float* __restrict__ ed,
                             float* __restrict__ m, float* __restrict__ eatt) {
    int i = blockIdx.x * 256 + threadIdx.x;
    if (i >= ET * 2) return;
    int e = i >> 1, h = i & 1;
    int s, d;
    if (e < E) { s = ei[e]; d = ei[E + e]; } else { s = e - E; d = s; }
    float z = es[s*2 + h] + ed[d*2 + h];
    z = z > 0.f ? z : 0.2f * z;
    eatt[i] = z;
    int* ai = (int*)(m + d*2 + h);
    int old = *ai;
    while (__int_as_float(old) < z) {
        int assumed = old;
        old = atomicCAS(ai, assumed, __float_as_int(z));
        if (old == assumed) break;
    }
}

__global__ void edge_exp_k(const int* __restrict__ ei, int E, int ET,
                           const float* __restrict__ m, float* __restrict__ s,
                           float* __restrict__ eatt) {
    int i = blockIdx.x * 256 + threadIdx.x;
    if (i >= ET * 2) return;
    int e = i >> 1, h = i & 1;
    int d = (e < E) ? ei[E + e] : e - E;
    float ex = __expf(eatt[i] - m[d*2 + h]);
    eatt[i] = ex;
    atomicAdd(s + d*2 + h, ex);
}

__global__ void edge_scatter_k(const int* __restrict__ ei, int E, int ET,
                               const float* __restrict__ xp, const float* __restrict__ eatt,
                               const float* __restrict__ s, float* __restrict__ out) {
    int gid = blockIdx.x * 256 + threadIdx.x;
    int e = gid >> 5;
    if (e >= ET) return;
    int c4 = gid & 31;
    int h = c4 >> 4;
    int sr, d;
    if (e < E) { sr = ei[e]; d = ei[E + e]; } else { sr = e - E; d = sr; }
    float alpha = eatt[e*2 + h] / s[d*2 + h];
    float4 v = *(const float4*)(xp + (size_t)sr * 128 + c4 * 4);
    float* o = out + (size_t)d * 128 + c4 * 4;
    atomicAdd(o + 0, v.x * alpha);
    atomicAdd(o + 1, v.y * alpha);
    atomicAdd(o + 2, v.z * alpha);
    atomicAdd(o + 3, v.w * alpha);
}

__global__ void bias_act_k(float* __restrict__ o, const float* __restrict__ b,
                           int total, int relu) {
    int i = blockIdx.x * 256 + threadIdx.x;
    if (i >= total) return;
    float v = o[i] + b[i & 127];
    if (relu) v = fmaxf(v, 0.f);
    o[i] = v;
}

// ---------------------------------------------------------------- LSTM step (fused)
// Per block: 16 nodes. g = [x_t|h_prev] @ [Wih|Whh]^T + bih + bhh  (512 gates/node),
// then gate nonlinearities, c/h update, and JK score contribution h.wsc, all fused.
__global__ __launch_bounds__(256)
void lstm_step_k(const float* __restrict__ Xt, float* __restrict__ hbuf, float* __restrict__ cbuf,
                 const float* __restrict__ Wih, const float* __restrict__ Whh,
                 const float* __restrict__ bih, const float* __restrict__ bhh,
                 const float* __restrict__ wsc, float* __restrict__ score, int first)
{
    __shared__ float a_s[16][17];
    __shared__ float w_s[512 * 17];   // W tile; reused as g[16][512] after K loop
    __shared__ float sc_s[16];
    int tid = threadIdx.x;
    int node0 = blockIdx.x * 16;
    if (tid < 16) sc_s[tid] = 0.f;
    int tj = tid & 63;
    int tn = tid >> 6;
    float acc[4][8];
    #pragma unroll
    for (int a = 0; a < 4; ++a)
        #pragma unroll
        for (int b = 0; b < 8; ++b) acc[a][b] = 0.f;

    int a_node = tid >> 4, a_kk = tid & 15;
    for (int kb = 0; kb < 16; ++kb) {
        int k0 = kb * 16;
        {   // A tile: 16 nodes x 16 k
            int k = k0 + a_kk;
            float v;
            if (k < 128) v = Xt[(size_t)(node0 + a_node) * 128 + k];
            else         v = first ? 0.f : hbuf[(size_t)(node0 + a_node) * 128 + (k - 128)];
            a_s[a_kk][a_node] = v;
        }
        // W tile: 512 x 16 (float4 loads, 8 per thread)
        const float* Wsrc; int koff;
        if (k0 < 128) { Wsrc = Wih; koff = k0; } else { Wsrc = Whh; koff = k0 - 128; }
        #pragma unroll
        for (int i = 0; i < 8; ++i) {
            int idx4 = tid + 256 * i;
            int j = idx4 >> 2;
            int kq = (idx4 & 3) * 4;
            float4 v = *(const float4*)(Wsrc + (size_t)j * 128 + koff + kq);
            float* dst = w_s + j * 17 + kq;
            dst[0] = v.x; dst[1] = v.y; dst[2] = v.z; dst[3] = v.w;
        }
        __syncthreads();
        #pragma unroll
        for (int kk = 0; kk < 16; ++kk) {
            float a[4];
            #pragma unroll
            for (int nn = 0; nn < 4; ++nn) a[nn] = a_s[kk][tn*4 + nn];
            #pragma unroll
            for (int jj = 0; jj < 8; ++jj) {
                float wv = w_s[(tj + 64*jj) * 17 + kk];
                #pragma unroll
                for (int nn = 0; nn < 4; ++nn)
                    acc[nn][jj] = fmaf(a[nn], wv, acc[nn][jj]);
            }
        }
        __syncthreads();
    }
    // gates -> LDS (reuse w_s as g[16][512])
    #pragma unroll
    for (int jj = 0; jj < 8; ++jj) {
        int j = tj + 64 * jj;
        float bj = bih[j] + bhh[j];
        #pragma unroll
        for (int nn = 0; nn < 4; ++nn)
            w_s[(tn*4 + nn) * 512 + j] = acc[nn][jj] + bj;
    }
    __syncthreads();
    // gate nonlinearities + c/h update + score contribution
    int k = tid & 127;
    float wk = wsc[k];
    #pragma unroll
    for (int r = 0; r < 8; ++r) {
        int u = tid + 256 * r;
        int node = u >> 7;
        const float* g = w_s + node * 512;
        float gi = g[k], gf = g[128 + k], gg = g[256 + k], go = g[384 + k];
        float si = 1.f / (1.f + __expf(-gi));
        float sf = 1.f / (1.f + __expf(-gf));
        float so = 1.f / (1.f + __expf(-go));
        float tg = tanhf(gg);
        size_t gidx = (size_t)(node0 + node) * 128 + k;
        float cp = first ? 0.f : cbuf[gidx];
        float cn = sf * cp + si * tg;
        float hn = so * tanhf(cn);
        cbuf[gidx] = cn;
        hbuf[gidx] = hn;
        float val = hn * wk;   // all 64 lanes of this wave share `node`
        #pragma unroll
        for (int off = 32; off > 0; off >>= 1)
            val += __shfl_xor(val, off);
        if ((tid & 63) == 0) atomicAdd(&sc_s[node], val);
    }
    __syncthreads();
    if (tid < 16) score[node0 + tid] += sc_s[tid];
}

// ---------------------------------------------------------------- JK combine + head
__global__ void jk_combine_k(const float* __restrict__ score, const float* __restrict__ xs0,
                             const float* __restrict__ xs1, const float* __restrict__ xs2,
                             float* __restrict__ jk, int N_) {
    int gid = blockIdx.x * 256 + threadIdx.x;
    int n = gid >> 5;
    if (n >= N_) return;
    int c = (gid & 31) * 4;
    float s0 = score[n], s1 = score[N_ + n], s2 = score[2*N_ + n];
    float mx = fmaxf(s0, fmaxf(s1, s2));
    float e0 = __expf(s0 - mx), e1 = __expf(s1 - mx), e2 = __expf(s2 - mx);
    float inv = 1.f / (e0 + e1 + e2);
    float a0 = e0 * inv, a1 = e1 * inv, a2 = e2 * inv;
    size_t off = (size_t)n * 128 + c;
    float4 x0 = *(const float4*)(xs0 + off);
    float4 x1 = *(const float4*)(xs1 + off);
    float4 x2 = *(const float4*)(xs2 + off);
    float4 o;
    o.x = a0*x0.x + a1*x1.x + a2*x2.x;
    o.y = a0*x0.y + a1*x1.y + a2*x2.y;
    o.z = a0*x0.z + a1*x1.z + a2*x2.z;
    o.w = a0*x0.w + a1*x1.w + a2*x2.w;
    *(float4*)(jk + off) = o;
}

__global__ void final_out_k(const float* __restrict__ h2, const float* __restrict__ ow,
                            const float* __restrict__ ob, float* __restrict__ out, int N_) {
    int n = blockIdx.x * 256 + threadIdx.x;
    if (n >= N_) return;
    float l[6];
    #pragma unroll
    for (int j = 0; j < 6; ++j) l[j] = ob[j];
    for (int c = 0; c < 64; c += 4) {
        float4 h4 = *(const float4*)(h2 + (size_t)n * 64 + c);
        #pragma unroll
        for (int j = 0; j < 6; ++j) {
            l[j] += h4.x * ow[j*64 + c + 0] + h4.y * ow[j*64 + c + 1]
                  + h4.z * ow[j*64 + c + 2] + h4.w * ow[j*64 + c + 3];
        }
    }
    float mx = l[0];
    #pragma unroll
    for (int j = 1; j < 6; ++j) mx = fmaxf(mx, l[j]);
    float se = 0.f;
    #pragma unroll
    for (int j = 0; j < 6; ++j) se += __expf(l[j] - mx);
    float ls = logf(se) + mx;
    #pragma unroll
    for (int j = 0; j < 6; ++j) out[(size_t)n * 6 + j] = l[j] - ls;
}

// ---------------------------------------------------------------- launch
extern "C" void kernel_launch(void* const* d_in, const int* in_sizes, int n_in,
                              void* d_out, int out_size, void* d_ws, size_t ws_size,
                              hipStream_t stream) {
    const float* x   = (const float*)d_in[0];
    const int*   ei  = (const int*)d_in[1];
    const float* W1  = (const float*)d_in[2];
    const float* a1s = (const float*)d_in[3];
    const float* a1d = (const float*)d_in[4];
    const float* b1  = (const float*)d_in[5];
    const float* Ws  = (const float*)d_in[6];
    const float* ass = (const float*)d_in[7];
    const float* asd = (const float*)d_in[8];
    const float* bs  = (const float*)d_in[9];
    const float* Wih = (const float*)d_in[10];
    const float* Whh = (const float*)d_in[11];
    const float* bih = (const float*)d_in[12];
    const float* bhh = (const float*)d_in[13];
    const float* jkw = (const float*)d_in[14];
    const float* jkb = (const float*)d_in[15];
    const float* l1w = (const float*)d_in[16];
    const float* l1b = (const float*)d_in[17];
    const float* l2w = (const float*)d_in[18];
    const float* l2b = (const float*)d_in[19];
    const float* ow  = (const float*)d_in[20];
    const float* ob  = (const float*)d_in[21];
    float* out = (float*)d_out;

    int Nn = in_sizes[0] / 128;
    int E  = in_sizes[1] / 2;
    int ET = E + Nn;

    float* w = (float*)d_ws;
    size_t F = (size_t)Nn * 128;
    float* xp    = w;
    float* xs0   = w + F;
    float* xs1   = w + 2*F;
    float* xs2   = w + 3*F;
    float* hbuf  = w + 4*F;
    float* cbuf  = w + 5*F;
    float* es    = w + 6*F;
    float* ed    = es + 2*Nn;
    float* mm    = ed + 2*Nn;
    float* ss    = mm + 2*Nn;
    float* score = ss + 2*Nn;
    float* eatt  = score + 3*Nn;
    float* h1 = xp;                    // xp dead after GAT layers
    float* h2 = xp + (size_t)Nn * 64;
    float* jk = hbuf;                  // hbuf dead after LSTM

    float* xs_arr[3] = {xs0, xs1, xs2};
    const float* in_l = x;

    for (int l = 0; l < 3; ++l) {
        const float* Wl  = (l == 0) ? W1  : Ws  + (size_t)(l-1) * 128 * 128;
        const float* asl = (l == 0) ? a1s : ass + (size_t)(l-1) * 128;
        const float* adl = (l == 0) ? a1d : asd + (size_t)(l-1) * 128;
        const float* bl  = (l == 0) ? b1  : bs  + (size_t)(l-1) * 128;
        float* out_l = xs_arr[l];

        dim3 g1(CDIV(Nn, 64), 2);
        gemm_k<<<g1, 256, 0, stream>>>(in_l, 128, in_l, 128, Wl, nullptr, xp, Nn, 128, 128, 0);
        att_sums_k<<<CDIV(Nn*2, 256), 256, 0, stream>>>(xp, asl, adl, es, ed, Nn);
        init_att_k<<<CDIV(Nn*2, 256), 256, 0, stream>>>(mm, ss, Nn*2);
        edge_logit_k<<<CDIV(ET*2, 256), 256, 0, stream>>>(ei, E, ET, es, ed, mm, eatt);
        edge_exp_k<<<CDIV(ET*2, 256), 256, 0, stream>>>(ei, E, ET, mm, ss, eatt);
        zero_f32<<<CDIV((int)F, 256), 256, 0, stream>>>(out_l, (int)F);
        edge_scatter_k<<<CDIV(ET*32, 256), 256, 0, stream>>>(ei, E, ET, xp, eatt, ss, out_l);
        bias_act_k<<<CDIV((int)F, 256), 256, 0, stream>>>(out_l, bl, (int)F, l > 0);
        in_l = out_l;
    }

    init_score_k<<<CDIV(3*Nn, 256), 256, 0, stream>>>(score, jkb, 3*Nn);
    // forward LSTM (dir 0)
    for (int t = 0; t < 3; ++t)
        lstm_step_k<<<Nn/16, 256, 0, stream>>>(xs_arr[t], hbuf, cbuf,
            Wih, Whh, bih, bhh, jkw, score + (size_t)t*Nn, t == 0);
    // backward LSTM (dir 1)
    for (int t = 2; t >= 0; --t)
        lstm_step_k<<<Nn/16, 256, 0, stream>>>(xs_arr[t], hbuf, cbuf,
            Wih + 512*128, Whh + 512*128, bih + 512, bhh + 512,
            jkw + 128, score + (size_t)t*Nn, t == 2);

    jk_combine_k<<<CDIV(Nn*32, 256), 256, 0, stream>>>(score, xs0, xs1, xs2, jk, Nn);
    gemm_k<<<dim3(CDIV(Nn, 64), 1), 256, 0, stream>>>(jk, 128, jk, 128, l1w, l1b, h1, Nn, 64, 128, 1);
    gemm_k<<<dim3(CDIV(Nn, 64), 1), 256, 0, stream>>>(h1, 64, x, 128, l2w, l2b, h2, Nn, 64, 192, 1);
    final_out_k<<<CDIV(Nn, 256), 256, 0, stream>>>(h2, ow, ob, out, Nn);
}

// Round 2
// 2502.709 us; speedup vs baseline: 2.7498x; 2.7498x over previous
//
#include <hip/hip_runtime.h>
#include <math.h>

#define CDIV(a,b) (((a)+(b)-1)/(b))

// ---------------------------------------------------------------- utils
__global__ void zero_i32(int* __restrict__ p, int n) {
    int i = blockIdx.x * 256 + threadIdx.x;
    if (i < n) p[i] = 0;
}
__global__ void init_score_k(float* __restrict__ sc, const float* __restrict__ b, int n) {
    int i = blockIdx.x * 256 + threadIdx.x;
    if (i < n) sc[i] = b[0];
}

// ---------------------------------------------------------------- CSR build
__global__ void hist_k(const int* __restrict__ ei, int E, int ET, int* __restrict__ deg) {
    int e = blockIdx.x * 256 + threadIdx.x;
    if (e >= ET) return;
    int d = (e < E) ? ei[E + e] : e - E;
    atomicAdd(deg + d, 1);
}

// single block, 1024 threads: exclusive scan of deg -> row_ptr (and cursor copy)
__global__ __launch_bounds__(1024)
void scan_k(const int* __restrict__ deg, int* __restrict__ row_ptr,
            int* __restrict__ cursor, int Nn) {
    __shared__ int ps[1024];
    int t = threadIdx.x;
    int chunk = CDIV(Nn, 1024);
    int b = t * chunk, e = min(b + chunk, Nn);
    int s = 0;
    for (int i = b; i < e; ++i) s += deg[i];
    ps[t] = s;
    __syncthreads();
    for (int off = 1; off < 1024; off <<= 1) {
        int v = (t >= off) ? ps[t - off] : 0;
        __syncthreads();
        ps[t] += v;
        __syncthreads();
    }
    int run = ps[t] - s;   // exclusive base for this chunk
    for (int i = b; i < e; ++i) {
        row_ptr[i] = run;
        cursor[i] = run;
        run += deg[i];
    }
}

__global__ void fill_k(const int* __restrict__ ei, int E, int ET,
                       int* __restrict__ cursor, int* __restrict__ csr_src) {
    int e = blockIdx.x * 256 + threadIdx.x;
    if (e >= ET) return;
    int s, d;
    if (e < E) { s = ei[e]; d = ei[E + e]; } else { s = e - E; d = s; }
    int pos = atomicAdd(cursor + d, 1);
    csr_src[pos] = s;
}

// ---------------------------------------------------------------- GEMM
// C[M,Nc] = act( [A1|A2][M,K] @ W[Nc,K]^T + bias ), A1 has K1 cols (row-stride K1),
// A2 covers k in [K1,K) with row-stride ldA2. K % 16 == 0, K1 % 16 == 0, Nc % 64 == 0.
__global__ __launch_bounds__(256)
void gemm_k(const float* __restrict__ A1, int K1,
            const float* __restrict__ A2, int ldA2,
            const float* __restrict__ W, const float* __restrict__ bias,
            float* __restrict__ C, int M, int Nc, int K, int relu)
{
    __shared__ __align__(16) float As[16][68];
    __shared__ __align__(16) float Bs[16][68];
    int tid = threadIdx.x;
    int bm = blockIdx.x * 64;
    int bn = blockIdx.y * 64;
    int tx = tid & 15, ty = tid >> 4;
    int lrow = tid >> 2;
    int lk4 = (tid & 3) * 4;
    float acc[4][4] = {};
    for (int kb = 0; kb < K; kb += 16) {
        int kg = kb + lk4;
        float4 va = make_float4(0.f, 0.f, 0.f, 0.f);
        int m = bm + lrow;
        if (m < M) {
            if (kg < K1) va = *(const float4*)(A1 + (size_t)m * K1 + kg);
            else         va = *(const float4*)(A2 + (size_t)m * ldA2 + (kg - K1));
        }
        As[lk4+0][lrow] = va.x; As[lk4+1][lrow] = va.y;
        As[lk4+2][lrow] = va.z; As[lk4+3][lrow] = va.w;
        float4 vb = *(const float4*)(W + (size_t)(bn + lrow) * K + kg);
        Bs[lk4+0][lrow] = vb.x; Bs[lk4+1][lrow] = vb.y;
        Bs[lk4+2][lrow] = vb.z; Bs[lk4+3][lrow] = vb.w;
        __syncthreads();
        #pragma unroll
        for (int kk = 0; kk < 16; ++kk) {
            float4 a4 = *(float4*)&As[kk][ty*4];
            float4 b4 = *(float4*)&Bs[kk][tx*4];
            float a[4] = {a4.x, a4.y, a4.z, a4.w};
            float b[4] = {b4.x, b4.y, b4.z, b4.w};
            #pragma unroll
            for (int i = 0; i < 4; ++i)
                #pragma unroll
                for (int j = 0; j < 4; ++j)
                    acc[i][j] = fmaf(a[i], b[j], acc[i][j]);
        }
        __syncthreads();
    }
    float4 bb = make_float4(0.f, 0.f, 0.f, 0.f);
    if (bias) bb = *(const float4*)(bias + bn + tx*4);
    #pragma unroll
    for (int i = 0; i < 4; ++i) {
        int m = bm + ty*4 + i;
        if (m >= M) continue;
        float4 v = make_float4(acc[i][0]+bb.x, acc[i][1]+bb.y, acc[i][2]+bb.z, acc[i][3]+bb.w);
        if (relu) { v.x=fmaxf(v.x,0.f); v.y=fmaxf(v.y,0.f); v.z=fmaxf(v.z,0.f); v.w=fmaxf(v.w,0.f); }
        *(float4*)(C + (size_t)m * Nc + bn + tx*4) = v;
    }
}

// ---------------------------------------------------------------- GAT pieces
__global__ void att_sums_k(const float* __restrict__ xp, const float* __restrict__ asrc,
                           const float* __restrict__ adst, float* __restrict__ es,
                           float* __restrict__ ed, int N_) {
    int i = blockIdx.x * 256 + threadIdx.x;
    if (i >= 2 * N_) return;
    int n = i >> 1, h = i & 1;
    const float* row = xp + (size_t)n * 128 + h * 64;
    const float* ws = asrc + h * 64;
    const float* wd = adst + h * 64;
    float s = 0.f, d = 0.f;
    for (int c = 0; c < 64; c += 4) {
        float4 v = *(const float4*)(row + c);
        float4 a = *(const float4*)(ws + c);
        float4 b = *(const float4*)(wd + c);
        s += v.x*a.x + v.y*a.y + v.z*a.z + v.w*a.w;
        d += v.x*b.x + v.y*b.y + v.z*b.z + v.w*b.w;
    }
    es[i] = s; ed[i] = d;
}

// One wave per node: segment softmax + weighted gather, no atomics.
__global__ __launch_bounds__(256)
void gat_agg_k(const int* __restrict__ csr_src, const int* __restrict__ row_ptr,
               const int* __restrict__ deg,
               const float* __restrict__ xp, const float* __restrict__ es,
               const float* __restrict__ ed, const float* __restrict__ bias,
               float* __restrict__ out, int Nn, int relu)
{
    int wid = (blockIdx.x * 256 + threadIdx.x) >> 6;
    int lane = threadIdx.x & 63;
    if (wid >= Nn) return;
    int n = wid;
    int beg = row_ptr[n];
    int dn = deg[n];
    float2 edv = *(const float2*)(ed + n * 2);

    // pass 1: online (max, sum) of exp over edges, both heads; cache first 64
    int   src_c = 0;
    float z0_c = 0.f, z1_c = 0.f;
    float m0 = -3e38f, m1 = -3e38f, s0 = 0.f, s1 = 0.f;
    for (int i = lane; i < dn; i += 64) {
        int s = csr_src[beg + i];
        float2 e2 = *(const float2*)(es + s * 2);
        float z0 = e2.x + edv.x; z0 = z0 > 0.f ? z0 : 0.2f * z0;
        float z1 = e2.y + edv.y; z1 = z1 > 0.f ? z1 : 0.2f * z1;
        if (i == lane) { src_c = s; z0_c = z0; z1_c = z1; }
        float nm0 = fmaxf(m0, z0);
        s0 = s0 * __expf(m0 - nm0) + __expf(z0 - nm0); m0 = nm0;
        float nm1 = fmaxf(m1, z1);
        s1 = s1 * __expf(m1 - nm1) + __expf(z1 - nm1); m1 = nm1;
    }
    #pragma unroll
    for (int off = 32; off; off >>= 1) {
        float om0 = __shfl_xor(m0, off), os0 = __shfl_xor(s0, off);
        float nm0 = fmaxf(m0, om0);
        s0 = s0 * __expf(m0 - nm0) + os0 * __expf(om0 - nm0); m0 = nm0;
        float om1 = __shfl_xor(m1, off), os1 = __shfl_xor(s1, off);
        float nm1 = fmaxf(m1, om1);
        s1 = s1 * __expf(m1 - nm1) + os1 * __expf(om1 - nm1); m1 = nm1;
    }
    float inv0 = 1.f / s0, inv1 = 1.f / s1;

    // pass 2: weighted gather, lane owns channels (lane, 64+lane)
    float acc0 = 0.f, acc1 = 0.f;
    if (dn <= 64) {
        for (int i = 0; i < dn; ++i) {
            int s = __shfl(src_c, i);
            float a0 = __expf(__shfl(z0_c, i) - m0) * inv0;
            float a1 = __expf(__shfl(z1_c, i) - m1) * inv1;
            const float* row = xp + (size_t)s * 128;
            acc0 = fmaf(row[lane], a0, acc0);
            acc1 = fmaf(row[64 + lane], a1, acc1);
        }
    } else {
        for (int i = 0; i < dn; ++i) {
            int s = csr_src[beg + i];
            float2 e2 = *(const float2*)(es + s * 2);
            float z0 = e2.x + edv.x; z0 = z0 > 0.f ? z0 : 0.2f * z0;
            float z1 = e2.y + edv.y; z1 = z1 > 0.f ? z1 : 0.2f * z1;
            float a0 = __expf(z0 - m0) * inv0;
            float a1 = __expf(z1 - m1) * inv1;
            const float* row = xp + (size_t)s * 128;
            acc0 = fmaf(row[lane], a0, acc0);
            acc1 = fmaf(row[64 + lane], a1, acc1);
        }
    }
    float v0 = acc0 + bias[lane];
    float v1 = acc1 + bias[64 + lane];
    if (relu) { v0 = fmaxf(v0, 0.f); v1 = fmaxf(v1, 0.f); }
    out[(size_t)n * 128 + lane] = v0;
    out[(size_t)n * 128 + 64 + lane] = v1;
}

// ---------------------------------------------------------------- LSTM step (fused)
__global__ __launch_bounds__(256)
void lstm_step_k(const float* __restrict__ Xt, float* __restrict__ hbuf, float* __restrict__ cbuf,
                 const float* __restrict__ Wih, const float* __restrict__ Whh,
                 const float* __restrict__ bih, const float* __restrict__ bhh,
                 const float* __restrict__ wsc, float* __restrict__ score, int first)
{
    __shared__ float a_s[16][17];
    __shared__ float w_s[512 * 17];   // W tile; reused as g[16][512] after K loop
    __shared__ float sc_s[16];
    int tid = threadIdx.x;
    int node0 = blockIdx.x * 16;
    if (tid < 16) sc_s[tid] = 0.f;
    int tj = tid & 63;
    int tn = tid >> 6;
    float acc[4][8];
    #pragma unroll
    for (int a = 0; a < 4; ++a)
        #pragma unroll
        for (int b = 0; b < 8; ++b) acc[a][b] = 0.f;

    int a_node = tid >> 4, a_kk = tid & 15;
    for (int kb = 0; kb < 16; ++kb) {
        int k0 = kb * 16;
        {   // A tile: 16 nodes x 16 k
            int k = k0 + a_kk;
            float v;
            if (k < 128) v = Xt[(size_t)(node0 + a_node) * 128 + k];
            else         v = first ? 0.f : hbuf[(size_t)(node0 + a_node) * 128 + (k - 128)];
            a_s[a_kk][a_node] = v;
        }
        // W tile: 512 x 16 (float4 loads, 8 per thread)
        const float* Wsrc; int koff;
        if (k0 < 128) { Wsrc = Wih; koff = k0; } else { Wsrc = Whh; koff = k0 - 128; }
        #pragma unroll
        for (int i = 0; i < 8; ++i) {
            int idx4 = tid + 256 * i;
            int j = idx4 >> 2;
            int kq = (idx4 & 3) * 4;
            float4 v = *(const float4*)(Wsrc + (size_t)j * 128 + koff + kq);
            float* dst = w_s + j * 17 + kq;
            dst[0] = v.x; dst[1] = v.y; dst[2] = v.z; dst[3] = v.w;
        }
        __syncthreads();
        #pragma unroll
        for (int kk = 0; kk < 16; ++kk) {
            float a[4];
            #pragma unroll
            for (int nn = 0; nn < 4; ++nn) a[nn] = a_s[kk][tn*4 + nn];
            #pragma unroll
            for (int jj = 0; jj < 8; ++jj) {
                float wv = w_s[(tj + 64*jj) * 17 + kk];
                #pragma unroll
                for (int nn = 0; nn < 4; ++nn)
                    acc[nn][jj] = fmaf(a[nn], wv, acc[nn][jj]);
            }
        }
        __syncthreads();
    }
    // gates -> LDS (reuse w_s as g[16][512])
    #pragma unroll
    for (int jj = 0; jj < 8; ++jj) {
        int j = tj + 64 * jj;
        float bj = bih[j] + bhh[j];
        #pragma unroll
        for (int nn = 0; nn < 4; ++nn)
            w_s[(tn*4 + nn) * 512 + j] = acc[nn][jj] + bj;
    }
    __syncthreads();
    // gate nonlinearities + c/h update + score contribution
    int k = tid & 127;
    float wk = wsc[k];
    #pragma unroll
    for (int r = 0; r < 8; ++r) {
        int u = tid + 256 * r;
        int node = u >> 7;
        const float* g = w_s + node * 512;
        float gi = g[k], gf = g[128 + k], gg = g[256 + k], go = g[384 + k];
        float si = 1.f / (1.f + __expf(-gi));
        float sf = 1.f / (1.f + __expf(-gf));
        float so = 1.f / (1.f + __expf(-go));
        float tg = tanhf(gg);
        size_t gidx = (size_t)(node0 + node) * 128 + k;
        float cp = first ? 0.f : cbuf[gidx];
        float cn = sf * cp + si * tg;
        float hn = so * tanhf(cn);
        cbuf[gidx] = cn;
        hbuf[gidx] = hn;
        float val = hn * wk;   // all 64 lanes of this wave share `node`
        #pragma unroll
        for (int off = 32; off > 0; off >>= 1)
            val += __shfl_xor(val, off);
        if ((tid & 63) == 0) atomicAdd(&sc_s[node], val);
    }
    __syncthreads();
    if (tid < 16) score[node0 + tid] += sc_s[tid];
}

// ---------------------------------------------------------------- JK combine + head
__global__ void jk_combine_k(const float* __restrict__ score, const float* __restrict__ xs0,
                             const float* __restrict__ xs1, const float* __restrict__ xs2,
                             float* __restrict__ jk, int N_) {
    int gid = blockIdx.x * 256 + threadIdx.x;
    int n = gid >> 5;
    if (n >= N_) return;
    int c = (gid & 31) * 4;
    float s0 = score[n], s1 = score[N_ + n], s2 = score[2*N_ + n];
    float mx = fmaxf(s0, fmaxf(s1, s2));
    float e0 = __expf(s0 - mx), e1 = __expf(s1 - mx), e2 = __expf(s2 - mx);
    float inv = 1.f / (e0 + e1 + e2);
    float a0 = e0 * inv, a1 = e1 * inv, a2 = e2 * inv;
    size_t off = (size_t)n * 128 + c;
    float4 x0 = *(const float4*)(xs0 + off);
    float4 x1 = *(const float4*)(xs1 + off);
    float4 x2 = *(const float4*)(xs2 + off);
    float4 o;
    o.x = a0*x0.x + a1*x1.x + a2*x2.x;
    o.y = a0*x0.y + a1*x1.y + a2*x2.y;
    o.z = a0*x0.z + a1*x1.z + a2*x2.z;
    o.w = a0*x0.w + a1*x1.w + a2*x2.w;
    *(float4*)(jk + off) = o;
}

__global__ void final_out_k(const float* __restrict__ h2, const float* __restrict__ ow,
                            const float* __restrict__ ob, float* __restrict__ out, int N_) {
    int n = blockIdx.x * 256 + threadIdx.x;
    if (n >= N_) return;
    float l[6];
    #pragma unroll
    for (int j = 0; j < 6; ++j) l[j] = ob[j];
    for (int c = 0; c < 64; c += 4) {
        float4 h4 = *(const float4*)(h2 + (size_t)n * 64 + c);
        #pragma unroll
        for (int j = 0; j < 6; ++j) {
            l[j] += h4.x * ow[j*64 + c + 0] + h4.y * ow[j*64 + c + 1]
                  + h4.z * ow[j*64 + c + 2] + h4.w * ow[j*64 + c + 3];
        }
    }
    float mx = l[0];
    #pragma unroll
    for (int j = 1; j < 6; ++j) mx = fmaxf(mx, l[j]);
    float se = 0.f;
    #pragma unroll
    for (int j = 0; j < 6; ++j) se += __expf(l[j] - mx);
    float ls = logf(se) + mx;
    #pragma unroll
    for (int j = 0; j < 6; ++j) out[(size_t)n * 6 + j] = l[j] - ls;
}

// ---------------------------------------------------------------- launch
extern "C" void kernel_launch(void* const* d_in, const int* in_sizes, int n_in,
                              void* d_out, int out_size, void* d_ws, size_t ws_size,
                              hipStream_t stream) {
    const float* x   = (const float*)d_in[0];
    const int*   ei  = (const int*)d_in[1];
    const float* W1  = (const float*)d_in[2];
    const float* a1s = (const float*)d_in[3];
    const float* a1d = (const float*)d_in[4];
    const float* b1  = (const float*)d_in[5];
    const float* Ws  = (const float*)d_in[6];
    const float* ass = (const float*)d_in[7];
    const float* asd = (const float*)d_in[8];
    const float* bs  = (const float*)d_in[9];
    const float* Wih = (const float*)d_in[10];
    const float* Whh = (const float*)d_in[11];
    const float* bih = (const float*)d_in[12];
    const float* bhh = (const float*)d_in[13];
    const float* jkw = (const float*)d_in[14];
    const float* jkb = (const float*)d_in[15];
    const float* l1w = (const float*)d_in[16];
    const float* l1b = (const float*)d_in[17];
    const float* l2w = (const float*)d_in[18];
    const float* l2b = (const float*)d_in[19];
    const float* ow  = (const float*)d_in[20];
    const float* ob  = (const float*)d_in[21];
    float* out = (float*)d_out;

    int Nn = in_sizes[0] / 128;
    int E  = in_sizes[1] / 2;
    int ET = E + Nn;

    float* w = (float*)d_ws;
    size_t F = (size_t)Nn * 128;
    float* xp    = w;
    float* xs0   = w + F;
    float* xs1   = w + 2*F;
    float* xs2   = w + 3*F;
    float* hbuf  = w + 4*F;
    float* cbuf  = w + 5*F;
    float* es    = w + 6*F;
    float* ed    = es + 2*Nn;
    float* score = ed + 2*Nn;
    int*   deg     = (int*)(score + 3*Nn);
    int*   row_ptr = deg + Nn;
    int*   cursor  = row_ptr + Nn;
    int*   csr_src = cursor + Nn;
    float* h1 = xp;                    // xp dead after GAT layers
    float* h2 = xp + (size_t)Nn * 64;
    float* jk = hbuf;                  // hbuf dead after LSTM

    // ---- CSR by destination (edges identical for all 3 layers)
    zero_i32<<<CDIV(Nn, 256), 256, 0, stream>>>(deg, Nn);
    hist_k<<<CDIV(ET, 256), 256, 0, stream>>>(ei, E, ET, deg);
    scan_k<<<1, 1024, 0, stream>>>(deg, row_ptr, cursor, Nn);
    fill_k<<<CDIV(ET, 256), 256, 0, stream>>>(ei, E, ET, cursor, csr_src);

    float* xs_arr[3] = {xs0, xs1, xs2};
    const float* in_l = x;

    for (int l = 0; l < 3; ++l) {
        const float* Wl  = (l == 0) ? W1  : Ws  + (size_t)(l-1) * 128 * 128;
        const float* asl = (l == 0) ? a1s : ass + (size_t)(l-1) * 128;
        const float* adl = (l == 0) ? a1d : asd + (size_t)(l-1) * 128;
        const float* bl  = (l == 0) ? b1  : bs  + (size_t)(l-1) * 128;
        float* out_l = xs_arr[l];

        gemm_k<<<dim3(CDIV(Nn, 64), 2), 256, 0, stream>>>(in_l, 128, in_l, 128, Wl, nullptr, xp, Nn, 128, 128, 0);
        att_sums_k<<<CDIV(Nn*2, 256), 256, 0, stream>>>(xp, asl, adl, es, ed, Nn);
        gat_agg_k<<<CDIV(Nn, 4), 256, 0, stream>>>(csr_src, row_ptr, deg, xp, es, ed, bl, out_l, Nn, l > 0);
        in_l = out_l;
    }

    init_score_k<<<CDIV(3*Nn, 256), 256, 0, stream>>>(score, jkb, 3*Nn);
    // forward LSTM (dir 0)
    for (int t = 0; t < 3; ++t)
        lstm_step_k<<<Nn/16, 256, 0, stream>>>(xs_arr[t], hbuf, cbuf,
            Wih, Whh, bih, bhh, jkw, score + (size_t)t*Nn, t == 0);
    // backward LSTM (dir 1)
    for (int t = 2; t >= 0; --t)
        lstm_step_k<<<Nn/16, 256, 0, stream>>>(xs_arr[t], hbuf, cbuf,
            Wih + 512*128, Whh + 512*128, bih + 512, bhh + 512,
            jkw + 128, score + (size_t)t*Nn, t == 2);

    jk_combine_k<<<CDIV(Nn*32, 256), 256, 0, stream>>>(score, xs0, xs1, xs2, jk, Nn);
    gemm_k<<<dim3(CDIV(Nn, 64), 1), 256, 0, stream>>>(jk, 128, jk, 128, l1w, l1b, h1, Nn, 64, 128, 1);
    gemm_k<<<dim3(CDIV(Nn, 64), 1), 256, 0, stream>>>(h1, 64, x, 128, l2w, l2b, h2, Nn, 64, 192, 1);
    final_out_k<<<CDIV(Nn, 256), 256, 0, stream>>>(h2, ow, ob, out, Nn);
}

// Round 3
// 1096.326 us; speedup vs baseline: 6.2774x; 2.2828x over previous
//
#include <hip/hip_runtime.h>
#include <math.h>

#define CDIV(a,b) (((a)+(b)-1)/(b))

typedef __attribute__((ext_vector_type(8))) short bfrag;
typedef __attribute__((ext_vector_type(4))) float ffrag;

__device__ inline unsigned short f2bf(float f) {
    unsigned int u = __float_as_uint(f);
    return (unsigned short)((u + 0x7fffu + ((u >> 16) & 1u)) >> 16);
}
__device__ inline float bf2f(unsigned short u) {
    return __uint_as_float(((unsigned int)u) << 16);
}
__device__ inline float sigf(float x) {
    return __builtin_amdgcn_rcpf(1.f + __expf(-x));
}
__device__ inline float tanhfast(float x) {
    float t = __expf(-2.f * fabsf(x));
    float r = (1.f - t) * __builtin_amdgcn_rcpf(1.f + t);
    return copysignf(r, x);
}

// ---------------------------------------------------------------- utils
__global__ void zero_i32(int* __restrict__ p, int n) {
    int i = blockIdx.x * 256 + threadIdx.x;
    if (i < n) p[i] = 0;
}
__global__ void init_score_k(float* __restrict__ sc, const float* __restrict__ b, int n) {
    int i = blockIdx.x * 256 + threadIdx.x;
    if (i < n) sc[i] = b[0];
}

// ---------------------------------------------------------------- CSR build
__global__ void hist_k(const int* __restrict__ ei, int E, int ET, int* __restrict__ deg) {
    int e = blockIdx.x * 256 + threadIdx.x;
    if (e >= ET) return;
    int d = (e < E) ? ei[E + e] : e - E;
    atomicAdd(deg + d, 1);
}

__global__ __launch_bounds__(1024)
void scan_k(const int* __restrict__ deg, int* __restrict__ row_ptr,
            int* __restrict__ cursor, int Nn) {
    __shared__ int ps[1024];
    int t = threadIdx.x;
    int chunk = CDIV(Nn, 1024);
    int b = t * chunk, e = min(b + chunk, Nn);
    int s = 0;
    for (int i = b; i < e; ++i) s += deg[i];
    ps[t] = s;
    __syncthreads();
    for (int off = 1; off < 1024; off <<= 1) {
        int v = (t >= off) ? ps[t - off] : 0;
        __syncthreads();
        ps[t] += v;
        __syncthreads();
    }
    int run = ps[t] - s;
    for (int i = b; i < e; ++i) {
        row_ptr[i] = run;
        cursor[i] = run;
        run += deg[i];
    }
}

__global__ void fill_k(const int* __restrict__ ei, int E, int ET,
                       int* __restrict__ cursor, int* __restrict__ csr_src) {
    int e = blockIdx.x * 256 + threadIdx.x;
    if (e >= ET) return;
    int s, d;
    if (e < E) { s = ei[e]; d = ei[E + e]; } else { s = e - E; d = s; }
    int pos = atomicAdd(cursor + d, 1);
    csr_src[pos] = s;
}

// ---------------------------------------------------------------- GEMM (f32 A)
__global__ __launch_bounds__(256)
void gemm_k(const float* __restrict__ A1, int K1,
            const float* __restrict__ A2, int ldA2,
            const float* __restrict__ W, const float* __restrict__ bias,
            float* __restrict__ C, int M, int Nc, int K, int relu)
{
    __shared__ __align__(16) float As[16][68];
    __shared__ __align__(16) float Bs[16][68];
    int tid = threadIdx.x;
    int bm = blockIdx.x * 64;
    int bn = blockIdx.y * 64;
    int tx = tid & 15, ty = tid >> 4;
    int lrow = tid >> 2;
    int lk4 = (tid & 3) * 4;
    float acc[4][4] = {};
    for (int kb = 0; kb < K; kb += 16) {
        int kg = kb + lk4;
        float4 va = make_float4(0.f, 0.f, 0.f, 0.f);
        int m = bm + lrow;
        if (m < M) {
            if (kg < K1) va = *(const float4*)(A1 + (size_t)m * K1 + kg);
            else         va = *(const float4*)(A2 + (size_t)m * ldA2 + (kg - K1));
        }
        As[lk4+0][lrow] = va.x; As[lk4+1][lrow] = va.y;
        As[lk4+2][lrow] = va.z; As[lk4+3][lrow] = va.w;
        float4 vb = *(const float4*)(W + (size_t)(bn + lrow) * K + kg);
        Bs[lk4+0][lrow] = vb.x; Bs[lk4+1][lrow] = vb.y;
        Bs[lk4+2][lrow] = vb.z; Bs[lk4+3][lrow] = vb.w;
        __syncthreads();
        #pragma unroll
        for (int kk = 0; kk < 16; ++kk) {
            float4 a4 = *(float4*)&As[kk][ty*4];
            float4 b4 = *(float4*)&Bs[kk][tx*4];
            float a[4] = {a4.x, a4.y, a4.z, a4.w};
            float b[4] = {b4.x, b4.y, b4.z, b4.w};
            #pragma unroll
            for (int i = 0; i < 4; ++i)
                #pragma unroll
                for (int j = 0; j < 4; ++j)
                    acc[i][j] = fmaf(a[i], b[j], acc[i][j]);
        }
        __syncthreads();
    }
    float4 bb = make_float4(0.f, 0.f, 0.f, 0.f);
    if (bias) bb = *(const float4*)(bias + bn + tx*4);
    #pragma unroll
    for (int i = 0; i < 4; ++i) {
        int m = bm + ty*4 + i;
        if (m >= M) continue;
        float4 v = make_float4(acc[i][0]+bb.x, acc[i][1]+bb.y, acc[i][2]+bb.z, acc[i][3]+bb.w);
        if (relu) { v.x=fmaxf(v.x,0.f); v.y=fmaxf(v.y,0.f); v.z=fmaxf(v.z,0.f); v.w=fmaxf(v.w,0.f); }
        *(float4*)(C + (size_t)m * Nc + bn + tx*4) = v;
    }
}

// ---------------------------------------------------------------- GEMM (bf16 A, K=128)
__global__ __launch_bounds__(256)
void gemm_bf_k(const unsigned short* __restrict__ A, const float* __restrict__ W,
               float* __restrict__ C, int M)
{
    __shared__ __align__(16) float As[16][68];
    __shared__ __align__(16) float Bs[16][68];
    int tid = threadIdx.x;
    int bm = blockIdx.x * 64;
    int bn = blockIdx.y * 64;
    int tx = tid & 15, ty = tid >> 4;
    int lrow = tid >> 2;
    int lk4 = (tid & 3) * 4;
    float acc[4][4] = {};
    for (int kb = 0; kb < 128; kb += 16) {
        int kg = kb + lk4;
        float4 va = make_float4(0.f, 0.f, 0.f, 0.f);
        int m = bm + lrow;
        if (m < M) {
            ushort4 u = *(const ushort4*)(A + (size_t)m * 128 + kg);
            va = make_float4(bf2f(u.x), bf2f(u.y), bf2f(u.z), bf2f(u.w));
        }
        As[lk4+0][lrow] = va.x; As[lk4+1][lrow] = va.y;
        As[lk4+2][lrow] = va.z; As[lk4+3][lrow] = va.w;
        float4 vb = *(const float4*)(W + (size_t)(bn + lrow) * 128 + kg);
        Bs[lk4+0][lrow] = vb.x; Bs[lk4+1][lrow] = vb.y;
        Bs[lk4+2][lrow] = vb.z; Bs[lk4+3][lrow] = vb.w;
        __syncthreads();
        #pragma unroll
        for (int kk = 0; kk < 16; ++kk) {
            float4 a4 = *(float4*)&As[kk][ty*4];
            float4 b4 = *(float4*)&Bs[kk][tx*4];
            float a[4] = {a4.x, a4.y, a4.z, a4.w};
            float b[4] = {b4.x, b4.y, b4.z, b4.w};
            #pragma unroll
            for (int i = 0; i < 4; ++i)
                #pragma unroll
                for (int j = 0; j < 4; ++j)
                    acc[i][j] = fmaf(a[i], b[j], acc[i][j]);
        }
        __syncthreads();
    }
    #pragma unroll
    for (int i = 0; i < 4; ++i) {
        int m = bm + ty*4 + i;
        if (m >= M) continue;
        float4 v = make_float4(acc[i][0], acc[i][1], acc[i][2], acc[i][3]);
        *(float4*)(C + (size_t)m * 128 + bn + tx*4) = v;
    }
}

// ---------------------------------------------------------------- GAT pieces
__global__ void att_sums_k(const float* __restrict__ xp, const float* __restrict__ asrc,
                           const float* __restrict__ adst, float* __restrict__ es,
                           float* __restrict__ ed, int N_) {
    int i = blockIdx.x * 256 + threadIdx.x;
    if (i >= 2 * N_) return;
    int n = i >> 1, h = i & 1;
    const float* row = xp + (size_t)n * 128 + h * 64;
    const float* ws = asrc + h * 64;
    const float* wd = adst + h * 64;
    float s = 0.f, d = 0.f;
    for (int c = 0; c < 64; c += 4) {
        float4 v = *(const float4*)(row + c);
        float4 a = *(const float4*)(ws + c);
        float4 b = *(const float4*)(wd + c);
        s += v.x*a.x + v.y*a.y + v.z*a.z + v.w*a.w;
        d += v.x*b.x + v.y*b.y + v.z*b.z + v.w*b.w;
    }
    es[i] = s; ed[i] = d;
}

// One wave per node: segment softmax + weighted gather, no atomics. bf16 output.
__global__ __launch_bounds__(256)
void gat_agg_k(const int* __restrict__ csr_src, const int* __restrict__ row_ptr,
               const int* __restrict__ deg,
               const float* __restrict__ xp, const float* __restrict__ es,
               const float* __restrict__ ed, const float* __restrict__ bias,
               unsigned short* __restrict__ out, int Nn, int relu)
{
    int wid = (blockIdx.x * 256 + threadIdx.x) >> 6;
    int lane = threadIdx.x & 63;
    if (wid >= Nn) return;
    int n = wid;
    int beg = row_ptr[n];
    int dn = deg[n];
    float2 edv = *(const float2*)(ed + n * 2);

    int   src_c = 0;
    float z0_c = 0.f, z1_c = 0.f;
    float m0 = -3e38f, m1 = -3e38f, s0 = 0.f, s1 = 0.f;
    for (int i = lane; i < dn; i += 64) {
        int s = csr_src[beg + i];
        float2 e2 = *(const float2*)(es + s * 2);
        float z0 = e2.x + edv.x; z0 = z0 > 0.f ? z0 : 0.2f * z0;
        float z1 = e2.y + edv.y; z1 = z1 > 0.f ? z1 : 0.2f * z1;
        if (i == lane) { src_c = s; z0_c = z0; z1_c = z1; }
        float nm0 = fmaxf(m0, z0);
        s0 = s0 * __expf(m0 - nm0) + __expf(z0 - nm0); m0 = nm0;
        float nm1 = fmaxf(m1, z1);
        s1 = s1 * __expf(m1 - nm1) + __expf(z1 - nm1); m1 = nm1;
    }
    #pragma unroll
    for (int off = 32; off; off >>= 1) {
        float om0 = __shfl_xor(m0, off), os0 = __shfl_xor(s0, off);
        float nm0 = fmaxf(m0, om0);
        s0 = s0 * __expf(m0 - nm0) + os0 * __expf(om0 - nm0); m0 = nm0;
        float om1 = __shfl_xor(m1, off), os1 = __shfl_xor(s1, off);
        float nm1 = fmaxf(m1, om1);
        s1 = s1 * __expf(m1 - nm1) + os1 * __expf(om1 - nm1); m1 = nm1;
    }
    float inv0 = 1.f / s0, inv1 = 1.f / s1;

    float acc0 = 0.f, acc1 = 0.f;
    if (dn <= 64) {
        for (int i = 0; i < dn; ++i) {
            int s = __shfl(src_c, i);
            float a0 = __expf(__shfl(z0_c, i) - m0) * inv0;
            float a1 = __expf(__shfl(z1_c, i) - m1) * inv1;
            const float* row = xp + (size_t)s * 128;
            acc0 = fmaf(row[lane], a0, acc0);
            acc1 = fmaf(row[64 + lane], a1, acc1);
        }
    } else {
        for (int i = 0; i < dn; ++i) {
            int s = csr_src[beg + i];
            float2 e2 = *(const float2*)(es + s * 2);
            float z0 = e2.x + edv.x; z0 = z0 > 0.f ? z0 : 0.2f * z0;
            float z1 = e2.y + edv.y; z1 = z1 > 0.f ? z1 : 0.2f * z1;
            float a0 = __expf(z0 - m0) * inv0;
            float a1 = __expf(z1 - m1) * inv1;
            const float* row = xp + (size_t)s * 128;
            acc0 = fmaf(row[lane], a0, acc0);
            acc1 = fmaf(row[64 + lane], a1, acc1);
        }
    }
    float v0 = acc0 + bias[lane];
    float v1 = acc1 + bias[64 + lane];
    if (relu) { v0 = fmaxf(v0, 0.f); v1 = fmaxf(v1, 0.f); }
    out[(size_t)n * 128 + lane] = f2bf(v0);
    out[(size_t)n * 128 + 64 + lane] = f2bf(v1);
}

// ---------------------------------------------------------------- LSTM weight pack
__global__ void pack_w_k(const float* __restrict__ Wih, const float* __restrict__ Whh,
                         const float* __restrict__ bih, const float* __restrict__ bhh,
                         unsigned short* __restrict__ Wp, float* __restrict__ bsum) {
    int i = blockIdx.x * 256 + threadIdx.x;
    if (i < 1024) bsum[i] = bih[i] + bhh[i];
    if (i >= 2 * 512 * 256) return;
    int k = i & 255, j = (i >> 8) & 511, d = i >> 17;
    float v = (k < 128) ? Wih[((size_t)d * 512 + j) * 128 + k]
                        : Whh[((size_t)d * 512 + j) * 128 + (k - 128)];
    Wp[i] = f2bf(v);
}

// ---------------------------------------------------------------- LSTM step (MFMA)
// Block: 32 nodes, 4 waves. Wave wv owns gate tiles t == wv (mod 4), so for a
// channel k the i/f/g/o gates (k, k+128, k+256, k+384) land in the same wave's
// accumulators (tiles m, m+2, m+4, m+6). No LDS GEMM staging; A/B fragments are
// 16B contiguous per-lane global loads (W is L2-resident).
__global__ __launch_bounds__(256)
void lstm_mfma_k(const unsigned short* __restrict__ Xt, unsigned short* __restrict__ hbuf,
                 float* __restrict__ cbuf, const unsigned short* __restrict__ Wp,
                 const float* __restrict__ bsum, const float* __restrict__ wsc,
                 float* __restrict__ score, int Nn, int first)
{
    __shared__ float sc_s[32];
    int tid = threadIdx.x;
    int wv = tid >> 6, lane = tid & 63;
    int col = lane & 15, kg = lane >> 4;
    int node0 = blockIdx.x * 32;
    if (tid < 32) sc_s[tid] = 0.f;
    __syncthreads();

    ffrag acc[2][8];
    #pragma unroll
    for (int a = 0; a < 2; ++a)
        #pragma unroll
        for (int m = 0; m < 8; ++m) acc[a][m] = (ffrag){0.f, 0.f, 0.f, 0.f};

    const unsigned short* Ar0 = Xt + (size_t)(node0 + col) * 128;
    const unsigned short* Ar1 = Xt + (size_t)(node0 + 16 + col) * 128;
    const unsigned short* Hr0 = hbuf + (size_t)(node0 + col) * 128;
    const unsigned short* Hr1 = hbuf + (size_t)(node0 + 16 + col) * 128;

    int nks = first ? 4 : 8;
    for (int ks = 0; ks < nks; ++ks) {
        int kk = ks * 32 + kg * 8;   // global k, 0..255
        bfrag a0, a1;
        if (kk < 128) { a0 = *(const bfrag*)(Ar0 + kk);       a1 = *(const bfrag*)(Ar1 + kk); }
        else          { a0 = *(const bfrag*)(Hr0 + kk - 128); a1 = *(const bfrag*)(Hr1 + kk - 128); }
        #pragma unroll
        for (int m = 0; m < 8; ++m) {
            int gj = 16 * (4 * m + wv) + col;
            bfrag b = *(const bfrag*)(Wp + (size_t)gj * 256 + kk);
            acc[0][m] = __builtin_amdgcn_mfma_f32_16x16x32_bf16(a0, b, acc[0][m], 0, 0, 0);
            acc[1][m] = __builtin_amdgcn_mfma_f32_16x16x32_bf16(a1, b, acc[1][m], 0, 0, 0);
        }
    }
    __syncthreads();   // all waves' hbuf reads complete before epilogue writes

    #pragma unroll
    for (int nt = 0; nt < 2; ++nt) {
        float part[4] = {0.f, 0.f, 0.f, 0.f};
        #pragma unroll
        for (int m = 0; m < 2; ++m) {
            int k = 16 * (4 * m + wv) + col;        // channel 0..127
            float bi = bsum[k], bff = bsum[128 + k], bg = bsum[256 + k], bo = bsum[384 + k];
            float wk = wsc[k];
            #pragma unroll
            for (int r = 0; r < 4; ++r) {
                int n = node0 + nt * 16 + kg * 4 + r;
                bool ok = (n < Nn);
                float gi = acc[nt][m][r]     + bi;
                float gf = acc[nt][m + 2][r] + bff;
                float gg = acc[nt][m + 4][r] + bg;
                float go = acc[nt][m + 6][r] + bo;
                float si = sigf(gi);
                float sf = sigf(gf);
                float so = sigf(go);
                float tg = tanhfast(gg);
                float cp = (first || !ok) ? 0.f : cbuf[(size_t)n * 128 + k];
                float cn = sf * cp + si * tg;
                float hn = so * tanhfast(cn);
                if (ok) {
                    cbuf[(size_t)n * 128 + k] = cn;
                    hbuf[(size_t)n * 128 + k] = f2bf(hn);
                    part[r] += hn * wk;
                }
            }
        }
        #pragma unroll
        for (int r = 0; r < 4; ++r) {
            float v = part[r];
            #pragma unroll
            for (int mk = 1; mk < 16; mk <<= 1) v += __shfl_xor(v, mk);
            if (col == 0) atomicAdd(&sc_s[nt * 16 + kg * 4 + r], v);
        }
    }
    __syncthreads();
    if (tid < 32) {
        int n = node0 + tid;
        if (n < Nn) score[n] += sc_s[tid];
    }
}

// ---------------------------------------------------------------- JK combine + head
__global__ void jk_combine_k(const float* __restrict__ score, const unsigned short* __restrict__ x0,
                             const unsigned short* __restrict__ x1, const unsigned short* __restrict__ x2,
                             float* __restrict__ jk, int N_) {
    int gid = blockIdx.x * 256 + threadIdx.x;
    int n = gid >> 5;
    if (n >= N_) return;
    int c = (gid & 31) * 4;
    float s0 = score[n], s1 = score[N_ + n], s2 = score[2*N_ + n];
    float mx = fmaxf(s0, fmaxf(s1, s2));
    float e0 = __expf(s0 - mx), e1 = __expf(s1 - mx), e2 = __expf(s2 - mx);
    float inv = 1.f / (e0 + e1 + e2);
    float a0 = e0 * inv, a1 = e1 * inv, a2 = e2 * inv;
    size_t off = (size_t)n * 128 + c;
    ushort4 u0 = *(const ushort4*)(x0 + off);
    ushort4 u1 = *(const ushort4*)(x1 + off);
    ushort4 u2 = *(const ushort4*)(x2 + off);
    float4 o;
    o.x = a0*bf2f(u0.x) + a1*bf2f(u1.x) + a2*bf2f(u2.x);
    o.y = a0*bf2f(u0.y) + a1*bf2f(u1.y) + a2*bf2f(u2.y);
    o.z = a0*bf2f(u0.z) + a1*bf2f(u1.z) + a2*bf2f(u2.z);
    o.w = a0*bf2f(u0.w) + a1*bf2f(u1.w) + a2*bf2f(u2.w);
    *(float4*)(jk + off) = o;
}

__global__ void final_out_k(const float* __restrict__ h2, const float* __restrict__ ow,
                            const float* __restrict__ ob, float* __restrict__ out, int N_) {
    int n = blockIdx.x * 256 + threadIdx.x;
    if (n >= N_) return;
    float l[6];
    #pragma unroll
    for (int j = 0; j < 6; ++j) l[j] = ob[j];
    for (int c = 0; c < 64; c += 4) {
        float4 h4 = *(const float4*)(h2 + (size_t)n * 64 + c);
        #pragma unroll
        for (int j = 0; j < 6; ++j) {
            l[j] += h4.x * ow[j*64 + c + 0] + h4.y * ow[j*64 + c + 1]
                  + h4.z * ow[j*64 + c + 2] + h4.w * ow[j*64 + c + 3];
        }
    }
    float mx = l[0];
    #pragma unroll
    for (int j = 1; j < 6; ++j) mx = fmaxf(mx, l[j]);
    float se = 0.f;
    #pragma unroll
    for (int j = 0; j < 6; ++j) se += __expf(l[j] - mx);
    float ls = logf(se) + mx;
    #pragma unroll
    for (int j = 0; j < 6; ++j) out[(size_t)n * 6 + j] = l[j] - ls;
}

// ---------------------------------------------------------------- launch
extern "C" void kernel_launch(void* const* d_in, const int* in_sizes, int n_in,
                              void* d_out, int out_size, void* d_ws, size_t ws_size,
                              hipStream_t stream) {
    const float* x   = (const float*)d_in[0];
    const int*   ei  = (const int*)d_in[1];
    const float* W1  = (const float*)d_in[2];
    const float* a1s = (const float*)d_in[3];
    const float* a1d = (const float*)d_in[4];
    const float* b1  = (const float*)d_in[5];
    const float* Ws  = (const float*)d_in[6];
    const float* ass = (const float*)d_in[7];
    const float* asd = (const float*)d_in[8];
    const float* bs  = (const float*)d_in[9];
    const float* Wih = (const float*)d_in[10];
    const float* Whh = (const float*)d_in[11];
    const float* bih = (const float*)d_in[12];
    const float* bhh = (const float*)d_in[13];
    const float* jkw = (const float*)d_in[14];
    const float* jkb = (const float*)d_in[15];
    const float* l1w = (const float*)d_in[16];
    const float* l1b = (const float*)d_in[17];
    const float* l2w = (const float*)d_in[18];
    const float* l2b = (const float*)d_in[19];
    const float* ow  = (const float*)d_in[20];
    const float* ob  = (const float*)d_in[21];
    float* out = (float*)d_out;

    int Nn = in_sizes[0] / 128;
    int E  = in_sizes[1] / 2;
    int ET = E + Nn;
    size_t Np = ((size_t)Nn + 31) & ~(size_t)31;
    size_t Fp = Np * 128;

    float* w = (float*)d_ws;
    float* xp    = w;                  // [Fp] f32; later h1 (Nn*64) + h2 (Nn*64)
    float* cbuf  = w + Fp;             // [Fp] f32; later jk
    float* es    = w + 2*Fp;           // [2Nn]
    float* ed    = es + 2*Nn;          // [2Nn]
    float* score = ed + 2*Nn;          // [3Nn]
    float* bsum  = score + 3*Nn;       // [1024]
    unsigned short* xsb0 = (unsigned short*)(bsum + 1024);
    unsigned short* xsb1 = xsb0 + Fp;
    unsigned short* xsb2 = xsb1 + Fp;
    unsigned short* hbuf = xsb2 + Fp;
    unsigned short* Wp   = hbuf + Fp;  // [2*512*256]
    int* deg     = (int*)(Wp + 2*512*256);
    int* row_ptr = deg + Nn;
    int* cursor  = row_ptr + Nn;
    int* csr_src = cursor + Nn;
    float* h1 = xp;
    float* h2 = xp + (size_t)Nn * 64;
    float* jk = cbuf;

    // ---- CSR by destination (edges identical for all 3 layers)
    zero_i32<<<CDIV(Nn, 256), 256, 0, stream>>>(deg, Nn);
    hist_k<<<CDIV(ET, 256), 256, 0, stream>>>(ei, E, ET, deg);
    scan_k<<<1, 1024, 0, stream>>>(deg, row_ptr, cursor, Nn);
    fill_k<<<CDIV(ET, 256), 256, 0, stream>>>(ei, E, ET, cursor, csr_src);
    pack_w_k<<<CDIV(2*512*256, 256), 256, 0, stream>>>(Wih, Whh, bih, bhh, Wp, bsum);

    unsigned short* xsb_arr[3] = {xsb0, xsb1, xsb2};

    for (int l = 0; l < 3; ++l) {
        const float* asl = (l == 0) ? a1s : ass + (size_t)(l-1) * 128;
        const float* adl = (l == 0) ? a1d : asd + (size_t)(l-1) * 128;
        const float* bl  = (l == 0) ? b1  : bs  + (size_t)(l-1) * 128;
        if (l == 0)
            gemm_k<<<dim3(CDIV(Nn, 64), 2), 256, 0, stream>>>(x, 128, x, 128, W1, nullptr, xp, Nn, 128, 128, 0);
        else
            gemm_bf_k<<<dim3(CDIV(Nn, 64), 2), 256, 0, stream>>>(xsb_arr[l-1], Ws + (size_t)(l-1)*128*128, xp, Nn);
        att_sums_k<<<CDIV(Nn*2, 256), 256, 0, stream>>>(xp, asl, adl, es, ed, Nn);
        gat_agg_k<<<CDIV(Nn, 4), 256, 0, stream>>>(csr_src, row_ptr, deg, xp, es, ed, bl, xsb_arr[l], Nn, l > 0);
    }

    init_score_k<<<CDIV(3*Nn, 256), 256, 0, stream>>>(score, jkb, 3*Nn);
    int nb = CDIV(Nn, 32);
    for (int t = 0; t < 3; ++t)
        lstm_mfma_k<<<nb, 256, 0, stream>>>(xsb_arr[t], hbuf, cbuf, Wp, bsum, jkw,
                                            score + (size_t)t*Nn, Nn, t == 0);
    for (int t = 2; t >= 0; --t)
        lstm_mfma_k<<<nb, 256, 0, stream>>>(xsb_arr[t], hbuf, cbuf, Wp + 512*256, bsum + 512,
                                            jkw + 128, score + (size_t)t*Nn, Nn, t == 2);

    jk_combine_k<<<CDIV(Nn*32, 256), 256, 0, stream>>>(score, xsb0, xsb1, xsb2, jk, Nn);
    gemm_k<<<dim3(CDIV(Nn, 64), 1), 256, 0, stream>>>(jk, 128, jk, 128, l1w, l1b, h1, Nn, 64, 128, 1);
    gemm_k<<<dim3(CDIV(Nn, 64), 1), 256, 0, stream>>>(h1, 64, x, 128, l2w, l2b, h2, Nn, 64, 192, 1);
    final_out_k<<<CDIV(Nn, 256), 256, 0, stream>>>(h2, ow, ob, out, Nn);
}

// Round 4
// 873.983 us; speedup vs baseline: 7.8743x; 1.2544x over previous
//
#include <hip/hip_runtime.h>
#include <math.h>

#define CDIV(a,b) (((a)+(b)-1)/(b))

typedef __attribute__((ext_vector_type(8))) short bfrag;
typedef __attribute__((ext_vector_type(4))) float ffrag;

__device__ inline unsigned short f2bf(float f) {
    unsigned int u = __float_as_uint(f);
    return (unsigned short)((u + 0x7fffu + ((u >> 16) & 1u)) >> 16);
}
__device__ inline float bf2f(unsigned short u) {
    return __uint_as_float(((unsigned int)u) << 16);
}
__device__ inline float sigf(float x) {
    return __builtin_amdgcn_rcpf(1.f + __expf(-x));
}
__device__ inline float tanhfast(float x) {
    float t = __expf(-2.f * fabsf(x));
    float r = (1.f - t) * __builtin_amdgcn_rcpf(1.f + t);
    return copysignf(r, x);
}

// ---------------------------------------------------------------- utils
__global__ void zero_i32(int* __restrict__ p, int n) {
    int i = blockIdx.x * 256 + threadIdx.x;
    if (i < n) p[i] = 0;
}
__global__ void init_score_k(float* __restrict__ sc, const float* __restrict__ b, int n) {
    int i = blockIdx.x * 256 + threadIdx.x;
    if (i < n) sc[i] = b[0];
}
__global__ void convert_bf_k(const float* __restrict__ src, unsigned short* __restrict__ dst, int n) {
    int i = blockIdx.x * 256 + threadIdx.x;
    if (i < n) dst[i] = f2bf(src[i]);
}

// ---------------------------------------------------------------- CSR build
__global__ void hist_k(const int* __restrict__ ei, int E, int ET, int* __restrict__ deg) {
    int e = blockIdx.x * 256 + threadIdx.x;
    if (e >= ET) return;
    int d = (e < E) ? ei[E + e] : e - E;
    atomicAdd(deg + d, 1);
}

// scan over deg: block-local (1024 elems/block) -> block partials
__global__ __launch_bounds__(256)
void scan1_k(const int* __restrict__ deg, int* __restrict__ row_ptr,
             int* __restrict__ part, int Nn) {
    __shared__ int ls[256];
    int t = threadIdx.x;
    int base = blockIdx.x * 1024 + t * 4;
    int v[4];
    #pragma unroll
    for (int j = 0; j < 4; ++j) v[j] = (base + j < Nn) ? deg[base + j] : 0;
    int s = v[0] + v[1] + v[2] + v[3];
    ls[t] = s;
    __syncthreads();
    for (int off = 1; off < 256; off <<= 1) {
        int o = (t >= off) ? ls[t - off] : 0;
        __syncthreads();
        ls[t] += o;
        __syncthreads();
    }
    int run = ls[t] - s;
    if (t == 255) part[blockIdx.x] = ls[255];
    #pragma unroll
    for (int j = 0; j < 4; ++j) {
        if (base + j < Nn) row_ptr[base + j] = run;
        run += v[j];
    }
}
// exclusive scan of <=64 block partials, one wave
__global__ void scan2_k(int* __restrict__ part, int nb) {
    int lane = threadIdx.x;
    int v = (lane < nb) ? part[lane] : 0;
    int orig = v;
    for (int off = 1; off < 64; off <<= 1) {
        int o = __shfl_up(v, off);
        if (lane >= off) v += o;
    }
    if (lane < nb) part[lane] = v - orig;
}
__global__ void scan3_k(const int* __restrict__ part, int* __restrict__ row_ptr,
                        int* __restrict__ cursor, int Nn) {
    int i = blockIdx.x * 256 + threadIdx.x;
    if (i >= Nn) return;
    int v = row_ptr[i] + part[i >> 10];
    row_ptr[i] = v;
    cursor[i] = v;
}

__global__ void fill_k(const int* __restrict__ ei, int E, int ET,
                       int* __restrict__ cursor, int* __restrict__ csr_src) {
    int e = blockIdx.x * 256 + threadIdx.x;
    if (e >= ET) return;
    int s, d;
    if (e < E) { s = ei[e]; d = ei[E + e]; } else { s = e - E; d = s; }
    int pos = atomicAdd(cursor + d, 1);
    csr_src[pos] = s;
}

// ---------------------------------------------------------------- weight packs
__global__ void pack_w_k(const float* __restrict__ Wih, const float* __restrict__ Whh,
                         const float* __restrict__ bih, const float* __restrict__ bhh,
                         unsigned short* __restrict__ Wp, float* __restrict__ bsum) {
    int i = blockIdx.x * 256 + threadIdx.x;
    if (i < 1024) bsum[i] = bih[i] + bhh[i];
    if (i >= 2 * 512 * 256) return;
    int k = i & 255, j = (i >> 8) & 511, d = i >> 17;
    float v = (k < 128) ? Wih[((size_t)d * 512 + j) * 128 + k]
                        : Whh[((size_t)d * 512 + j) * 128 + (k - 128)];
    Wp[i] = f2bf(v);
}

// pack W1|Ws|l1w|l2w into one bf16 buffer (row-major [out, k] preserved)
__global__ void pack_wb_k(const float* __restrict__ W1, const float* __restrict__ Ws,
                          const float* __restrict__ l1w, const float* __restrict__ l2w,
                          unsigned short* __restrict__ wb) {
    int i = blockIdx.x * 256 + threadIdx.x;
    if (i >= 69632) return;
    float v;
    if (i < 16384)      v = W1[i];
    else if (i < 49152) v = Ws[i - 16384];
    else if (i < 57344) v = l1w[i - 49152];
    else                v = l2w[i - 57344];
    wb[i] = f2bf(v);
}

// ---------------------------------------------------------------- MFMA GEMM
// C[M, NT*16] = act(A_bf16[M,K] @ Wb_bf16[NT*16,K]^T + bias)
// A = [A1 (K1 cols) | A2 (rest, stride ldA2)]. K,K1 multiples of 32/8.
// FUSE: also emit es/ed = per-head dot of raw output with asl/adl.
template<int NT, int K, int K1, bool RELU, bool FUSE, bool BFOUT>
__global__ __launch_bounds__(256)
void gemm_mfma_k(const unsigned short* __restrict__ A1, const unsigned short* __restrict__ A2,
                 int ldA2, const unsigned short* __restrict__ Wb, const float* __restrict__ bias,
                 unsigned short* __restrict__ Cb, float* __restrict__ Cf,
                 const float* __restrict__ asl, const float* __restrict__ adl,
                 float* __restrict__ es, float* __restrict__ ed, int M)
{
    int tid = threadIdx.x;
    int wv = tid >> 6, lane = tid & 63;
    int col = lane & 15, kg = lane >> 4;
    int row0 = blockIdx.x * 64 + wv * 16;
    int mrow = row0 + col;
    bool mok = mrow < M;

    ffrag acc[NT];
    #pragma unroll
    for (int t = 0; t < NT; ++t) acc[t] = (ffrag){0.f, 0.f, 0.f, 0.f};

    #pragma unroll
    for (int ks = 0; ks < K / 32; ++ks) {
        int kk = ks * 32 + kg * 8;
        bfrag a = (bfrag){0,0,0,0,0,0,0,0};
        if (mok) {
            if (kk < K1) a = *(const bfrag*)(A1 + (size_t)mrow * K1 + kk);
            else         a = *(const bfrag*)(A2 + (size_t)mrow * ldA2 + (kk - K1));
        }
        #pragma unroll
        for (int t = 0; t < NT; ++t) {
            bfrag b = *(const bfrag*)(Wb + (size_t)(t * 16 + col) * K + kk);
            acc[t] = __builtin_amdgcn_mfma_f32_16x16x32_bf16(a, b, acc[t], 0, 0, 0);
        }
    }

    #pragma unroll
    for (int r = 0; r < 4; ++r) {
        int n = row0 + kg * 4 + r;
        bool ok = n < M;
        float e0 = 0.f, e1 = 0.f, d0 = 0.f, d1 = 0.f;
        #pragma unroll
        for (int t = 0; t < NT; ++t) {
            float v = acc[t][r];
            if (FUSE) {
                int ch = t * 16 + col;
                if (t < NT / 2) { e0 = fmaf(v, asl[ch], e0); d0 = fmaf(v, adl[ch], d0); }
                else            { e1 = fmaf(v, asl[ch], e1); d1 = fmaf(v, adl[ch], d1); }
            }
            if (bias) v += bias[t * 16 + col];
            if (RELU) v = fmaxf(v, 0.f);
            if (ok) {
                if (BFOUT) Cb[(size_t)n * (NT * 16) + t * 16 + col] = f2bf(v);
                else       Cf[(size_t)n * (NT * 16) + t * 16 + col] = v;
            }
        }
        if (FUSE) {
            #pragma unroll
            for (int mk = 1; mk < 16; mk <<= 1) {
                e0 += __shfl_xor(e0, mk); e1 += __shfl_xor(e1, mk);
                d0 += __shfl_xor(d0, mk); d1 += __shfl_xor(d1, mk);
            }
            if (col == 0 && ok) {
                es[n * 2] = e0; es[n * 2 + 1] = e1;
                ed[n * 2] = d0; ed[n * 2 + 1] = d1;
            }
        }
    }
}

// ---------------------------------------------------------------- GAT aggregate
// One wave per node: segment softmax + weighted gather (bf16 rows), no atomics.
__global__ __launch_bounds__(256)
void gat_agg_k(const int* __restrict__ csr_src, const int* __restrict__ row_ptr,
               const int* __restrict__ deg,
               const unsigned short* __restrict__ xpb, const float* __restrict__ es,
               const float* __restrict__ ed, const float* __restrict__ bias,
               unsigned short* __restrict__ out, int Nn, int relu)
{
    int wid = (blockIdx.x * 256 + threadIdx.x) >> 6;
    int lane = threadIdx.x & 63;
    if (wid >= Nn) return;
    int n = wid;
    int beg = row_ptr[n];
    int dn = deg[n];
    float2 edv = *(const float2*)(ed + n * 2);

    int   src_c = 0;
    float z0_c = 0.f, z1_c = 0.f;
    float m0 = -3e38f, m1 = -3e38f, s0 = 0.f, s1 = 0.f;
    for (int i = lane; i < dn; i += 64) {
        int s = csr_src[beg + i];
        float2 e2 = *(const float2*)(es + s * 2);
        float z0 = e2.x + edv.x; z0 = z0 > 0.f ? z0 : 0.2f * z0;
        float z1 = e2.y + edv.y; z1 = z1 > 0.f ? z1 : 0.2f * z1;
        if (i == lane) { src_c = s; z0_c = z0; z1_c = z1; }
        float nm0 = fmaxf(m0, z0);
        s0 = s0 * __expf(m0 - nm0) + __expf(z0 - nm0); m0 = nm0;
        float nm1 = fmaxf(m1, z1);
        s1 = s1 * __expf(m1 - nm1) + __expf(z1 - nm1); m1 = nm1;
    }
    #pragma unroll
    for (int off = 32; off; off >>= 1) {
        float om0 = __shfl_xor(m0, off), os0 = __shfl_xor(s0, off);
        float nm0 = fmaxf(m0, om0);
        s0 = s0 * __expf(m0 - nm0) + os0 * __expf(om0 - nm0); m0 = nm0;
        float om1 = __shfl_xor(m1, off), os1 = __shfl_xor(s1, off);
        float nm1 = fmaxf(m1, om1);
        s1 = s1 * __expf(m1 - nm1) + os1 * __expf(om1 - nm1); m1 = nm1;
    }
    float inv0 = 1.f / s0, inv1 = 1.f / s1;

    // lane owns channels (2*lane, 2*lane+1); head = lane<32 ? 0 : 1
    float acc0 = 0.f, acc1 = 0.f;
    if (dn <= 64) {
        for (int i = 0; i < dn; ++i) {
            int s = __shfl(src_c, i);
            float a0 = __expf(__shfl(z0_c, i) - m0) * inv0;
            float a1 = __expf(__shfl(z1_c, i) - m1) * inv1;
            float aw = (lane < 32) ? a0 : a1;
            unsigned int u = *(const unsigned int*)(xpb + (size_t)s * 128 + 2 * lane);
            acc0 = fmaf(bf2f((unsigned short)(u & 0xffff)), aw, acc0);
            acc1 = fmaf(bf2f((unsigned short)(u >> 16)), aw, acc1);
        }
    } else {
        for (int i = 0; i < dn; ++i) {
            int s = csr_src[beg + i];
            float2 e2 = *(const float2*)(es + s * 2);
            float z0 = e2.x + edv.x; z0 = z0 > 0.f ? z0 : 0.2f * z0;
            float z1 = e2.y + edv.y; z1 = z1 > 0.f ? z1 : 0.2f * z1;
            float a0 = __expf(z0 - m0) * inv0;
            float a1 = __expf(z1 - m1) * inv1;
            float aw = (lane < 32) ? a0 : a1;
            unsigned int u = *(const unsigned int*)(xpb + (size_t)s * 128 + 2 * lane);
            acc0 = fmaf(bf2f((unsigned short)(u & 0xffff)), aw, acc0);
            acc1 = fmaf(bf2f((unsigned short)(u >> 16)), aw, acc1);
        }
    }
    float2 bb = *(const float2*)(bias + 2 * lane);
    float v0 = acc0 + bb.x;
    float v1 = acc1 + bb.y;
    if (relu) { v0 = fmaxf(v0, 0.f); v1 = fmaxf(v1, 0.f); }
    unsigned int o = (unsigned int)f2bf(v0) | ((unsigned int)f2bf(v1) << 16);
    *(unsigned int*)(out + (size_t)n * 128 + 2 * lane) = o;
}

// ---------------------------------------------------------------- LSTM step (both dirs)
// grid (nb, 2): blockIdx.y = direction. Block: 32 nodes, 4 waves; wave wv owns
// gate tiles t == wv (mod 4) so i/f/g/o for a channel stay in-wave.
__global__ __launch_bounds__(256)
void lstm2_k(const unsigned short* __restrict__ X0, const unsigned short* __restrict__ X1,
             unsigned short* __restrict__ hbufB, float* __restrict__ cbufB,
             const unsigned short* __restrict__ WpB, const float* __restrict__ bsumB,
             const float* __restrict__ jkw, float* __restrict__ scA, float* __restrict__ scB,
             int Nn, size_t Fp, int first)
{
    int dir = blockIdx.y;
    const unsigned short* Xt = dir ? X1 : X0;
    unsigned short* hbuf = hbufB + (size_t)dir * Fp;
    float* cbuf = cbufB + (size_t)dir * Fp;
    const unsigned short* Wp = WpB + (size_t)dir * 512 * 256;
    const float* bsum = bsumB + dir * 512;
    const float* wsc = jkw + dir * 128;
    float* score = dir ? scB : scA;

    __shared__ float sc_s[32];
    int tid = threadIdx.x;
    int wv = tid >> 6, lane = tid & 63;
    int col = lane & 15, kg = lane >> 4;
    int node0 = blockIdx.x * 32;
    if (tid < 32) sc_s[tid] = 0.f;
    __syncthreads();

    ffrag acc[2][8];
    #pragma unroll
    for (int a = 0; a < 2; ++a)
        #pragma unroll
        for (int m = 0; m < 8; ++m) acc[a][m] = (ffrag){0.f, 0.f, 0.f, 0.f};

    const unsigned short* Ar0 = Xt + (size_t)(node0 + col) * 128;
    const unsigned short* Ar1 = Xt + (size_t)(node0 + 16 + col) * 128;
    const unsigned short* Hr0 = hbuf + (size_t)(node0 + col) * 128;
    const unsigned short* Hr1 = hbuf + (size_t)(node0 + 16 + col) * 128;

    int nks = first ? 4 : 8;
    for (int ks = 0; ks < nks; ++ks) {
        int kk = ks * 32 + kg * 8;
        bfrag a0, a1;
        if (kk < 128) { a0 = *(const bfrag*)(Ar0 + kk);       a1 = *(const bfrag*)(Ar1 + kk); }
        else          { a0 = *(const bfrag*)(Hr0 + kk - 128); a1 = *(const bfrag*)(Hr1 + kk - 128); }
        #pragma unroll
        for (int m = 0; m < 8; ++m) {
            int gj = 16 * (4 * m + wv) + col;
            bfrag b = *(const bfrag*)(Wp + (size_t)gj * 256 + kk);
            acc[0][m] = __builtin_amdgcn_mfma_f32_16x16x32_bf16(a0, b, acc[0][m], 0, 0, 0);
            acc[1][m] = __builtin_amdgcn_mfma_f32_16x16x32_bf16(a1, b, acc[1][m], 0, 0, 0);
        }
    }
    __syncthreads();   // hbuf reads complete before epilogue writes

    #pragma unroll
    for (int nt = 0; nt < 2; ++nt) {
        float part[4] = {0.f, 0.f, 0.f, 0.f};
        #pragma unroll
        for (int m = 0; m < 2; ++m) {
            int k = 16 * (4 * m + wv) + col;
            float bi = bsum[k], bff = bsum[128 + k], bg = bsum[256 + k], bo = bsum[384 + k];
            float wk = wsc[k];
            #pragma unroll
            for (int r = 0; r < 4; ++r) {
                int n = node0 + nt * 16 + kg * 4 + r;
                bool ok = (n < Nn);
                float gi = acc[nt][m][r]     + bi;
                float gf = acc[nt][m + 2][r] + bff;
                float gg = acc[nt][m + 4][r] + bg;
                float go = acc[nt][m + 6][r] + bo;
                float si = sigf(gi);
                float sf = sigf(gf);
                float so = sigf(go);
                float tg = tanhfast(gg);
                float cp = (first || !ok) ? 0.f : cbuf[(size_t)n * 128 + k];
                float cn = sf * cp + si * tg;
                float hn = so * tanhfast(cn);
                if (ok) {
                    cbuf[(size_t)n * 128 + k] = cn;
                    hbuf[(size_t)n * 128 + k] = f2bf(hn);
                    part[r] += hn * wk;
                }
            }
        }
        #pragma unroll
        for (int r = 0; r < 4; ++r) {
            float v = part[r];
            #pragma unroll
            for (int mk = 1; mk < 16; mk <<= 1) v += __shfl_xor(v, mk);
            if (col == 0) atomicAdd(&sc_s[nt * 16 + kg * 4 + r], v);
        }
    }
    __syncthreads();
    if (tid < 32) {
        int n = node0 + tid;
        if (n < Nn) atomicAdd(&score[n], sc_s[tid]);  // both dirs hit same t at i=1
    }
}

// ---------------------------------------------------------------- JK combine + head
__global__ void jk_combine_k(const float* __restrict__ score, const unsigned short* __restrict__ x0,
                             const unsigned short* __restrict__ x1, const unsigned short* __restrict__ x2,
                             unsigned short* __restrict__ jkb, int N_) {
    int gid = blockIdx.x * 256 + threadIdx.x;
    int n = gid >> 5;
    if (n >= N_) return;
    int c = (gid & 31) * 4;
    float s0 = score[n], s1 = score[N_ + n], s2 = score[2*N_ + n];
    float mx = fmaxf(s0, fmaxf(s1, s2));
    float e0 = __expf(s0 - mx), e1 = __expf(s1 - mx), e2 = __expf(s2 - mx);
    float inv = 1.f / (e0 + e1 + e2);
    float a0 = e0 * inv, a1 = e1 * inv, a2 = e2 * inv;
    size_t off = (size_t)n * 128 + c;
    ushort4 u0 = *(const ushort4*)(x0 + off);
    ushort4 u1 = *(const ushort4*)(x1 + off);
    ushort4 u2 = *(const ushort4*)(x2 + off);
    ushort4 o;
    o.x = f2bf(a0*bf2f(u0.x) + a1*bf2f(u1.x) + a2*bf2f(u2.x));
    o.y = f2bf(a0*bf2f(u0.y) + a1*bf2f(u1.y) + a2*bf2f(u2.y));
    o.z = f2bf(a0*bf2f(u0.z) + a1*bf2f(u1.z) + a2*bf2f(u2.z));
    o.w = f2bf(a0*bf2f(u0.w) + a1*bf2f(u1.w) + a2*bf2f(u2.w));
    *(ushort4*)(jkb + off) = o;
}

__global__ void final_out_k(const float* __restrict__ h2, const float* __restrict__ ow,
                            const float* __restrict__ ob, float* __restrict__ out, int N_) {
    int n = blockIdx.x * 256 + threadIdx.x;
    if (n >= N_) return;
    float l[6];
    #pragma unroll
    for (int j = 0; j < 6; ++j) l[j] = ob[j];
    for (int c = 0; c < 64; c += 4) {
        float4 h4 = *(const float4*)(h2 + (size_t)n * 64 + c);
        #pragma unroll
        for (int j = 0; j < 6; ++j) {
            l[j] += h4.x * ow[j*64 + c + 0] + h4.y * ow[j*64 + c + 1]
                  + h4.z * ow[j*64 + c + 2] + h4.w * ow[j*64 + c + 3];
        }
    }
    float mx = l[0];
    #pragma unroll
    for (int j = 1; j < 6; ++j) mx = fmaxf(mx, l[j]);
    float se = 0.f;
    #pragma unroll
    for (int j = 0; j < 6; ++j) se += __expf(l[j] - mx);
    float ls = logf(se) + mx;
    #pragma unroll
    for (int j = 0; j < 6; ++j) out[(size_t)n * 6 + j] = l[j] - ls;
}

// ---------------------------------------------------------------- launch
extern "C" void kernel_launch(void* const* d_in, const int* in_sizes, int n_in,
                              void* d_out, int out_size, void* d_ws, size_t ws_size,
                              hipStream_t stream) {
    const float* x   = (const float*)d_in[0];
    const int*   ei  = (const int*)d_in[1];
    const float* W1  = (const float*)d_in[2];
    const float* a1s = (const float*)d_in[3];
    const float* a1d = (const float*)d_in[4];
    const float* b1  = (const float*)d_in[5];
    const float* Ws  = (const float*)d_in[6];
    const float* ass = (const float*)d_in[7];
    const float* asd = (const float*)d_in[8];
    const float* bs  = (const float*)d_in[9];
    const float* Wih = (const float*)d_in[10];
    const float* Whh = (const float*)d_in[11];
    const float* bih = (const float*)d_in[12];
    const float* bhh = (const float*)d_in[13];
    const float* jkw = (const float*)d_in[14];
    const float* jkb_b = (const float*)d_in[15];
    const float* l1w = (const float*)d_in[16];
    const float* l1b = (const float*)d_in[17];
    const float* l2w = (const float*)d_in[18];
    const float* l2b = (const float*)d_in[19];
    const float* ow  = (const float*)d_in[20];
    const float* ob  = (const float*)d_in[21];
    float* out = (float*)d_out;

    int Nn = in_sizes[0] / 128;
    int E  = in_sizes[1] / 2;
    int ET = E + Nn;
    size_t Np = ((size_t)Nn + 31) & ~(size_t)31;
    size_t Fp = Np * 128;

    float* w = (float*)d_ws;
    float* cbuf  = w;                    // [2*Fp] f32; reused as h2 after LSTM
    float* es    = w + 2*Fp;             // [2Nn]
    float* ed    = es + 2*Nn;
    float* score = ed + 2*Nn;            // [3Nn]
    float* bsum  = score + 3*Nn;         // [1024]
    unsigned short* xb   = (unsigned short*)(bsum + 1024);  // [Fp]
    unsigned short* xpb  = xb + Fp;      // [Fp]; reused as jkb
    unsigned short* xsb0 = xpb + Fp;
    unsigned short* xsb1 = xsb0 + Fp;
    unsigned short* xsb2 = xsb1 + Fp;
    unsigned short* hbuf = xsb2 + Fp;    // [2*Fp]; reused as h1b
    unsigned short* Wp   = hbuf + 2*Fp;  // [2*512*256]
    unsigned short* wb   = Wp + 2*512*256; // [69632]
    int* deg     = (int*)(wb + 69632);
    int* row_ptr = deg + Nn;
    int* cursor  = row_ptr + Nn;
    int* part    = cursor + Nn;          // [64]
    int* csr_src = part + 64;            // [ET]
    float* h2 = cbuf;
    unsigned short* jkb = xpb;
    unsigned short* h1b = hbuf;

    // ---- CSR by destination (edges identical for all 3 layers)
    int nb1 = CDIV(Nn, 1024);
    zero_i32<<<CDIV(Nn, 256), 256, 0, stream>>>(deg, Nn);
    hist_k<<<CDIV(ET, 256), 256, 0, stream>>>(ei, E, ET, deg);
    scan1_k<<<nb1, 256, 0, stream>>>(deg, row_ptr, part, Nn);
    scan2_k<<<1, 64, 0, stream>>>(part, nb1);
    scan3_k<<<CDIV(Nn, 256), 256, 0, stream>>>(part, row_ptr, cursor, Nn);
    fill_k<<<CDIV(ET, 256), 256, 0, stream>>>(ei, E, ET, cursor, csr_src);

    // ---- packs / converts
    pack_w_k<<<CDIV(2*512*256, 256), 256, 0, stream>>>(Wih, Whh, bih, bhh, Wp, bsum);
    pack_wb_k<<<CDIV(69632, 256), 256, 0, stream>>>(W1, Ws, l1w, l2w, wb);
    convert_bf_k<<<CDIV(Nn*128, 256), 256, 0, stream>>>(x, xb, Nn*128);

    unsigned short* xsb_arr[3] = {xsb0, xsb1, xsb2};
    int gblk = CDIV(Nn, 64);

    for (int l = 0; l < 3; ++l) {
        const float* asl = (l == 0) ? a1s : ass + (size_t)(l-1) * 128;
        const float* adl = (l == 0) ? a1d : asd + (size_t)(l-1) * 128;
        const float* bl  = (l == 0) ? b1  : bs  + (size_t)(l-1) * 128;
        const unsigned short* Ain = (l == 0) ? xb : xsb_arr[l-1];
        const unsigned short* Wbl = wb + (size_t)l * 16384;
        gemm_mfma_k<8,128,128,false,true,true><<<gblk, 256, 0, stream>>>(
            Ain, Ain, 128, Wbl, nullptr, xpb, nullptr, asl, adl, es, ed, Nn);
        gat_agg_k<<<CDIV(Nn, 4), 256, 0, stream>>>(csr_src, row_ptr, deg, xpb, es, ed, bl,
                                                   xsb_arr[l], Nn, l > 0);
    }

    init_score_k<<<CDIV(3*Nn, 256), 256, 0, stream>>>(score, jkb_b, 3*Nn);
    int nb = CDIV(Nn, 32);
    for (int i = 0; i < 3; ++i)
        lstm2_k<<<dim3(nb, 2), 256, 0, stream>>>(xsb_arr[i], xsb_arr[2-i], hbuf, cbuf,
            Wp, bsum, jkw, score + (size_t)i*Nn, score + (size_t)(2-i)*Nn, Nn, Fp, i == 0);

    jk_combine_k<<<CDIV(Nn*32, 256), 256, 0, stream>>>(score, xsb0, xsb1, xsb2, jkb, Nn);
    gemm_mfma_k<4,128,128,true,false,true><<<gblk, 256, 0, stream>>>(
        jkb, jkb, 128, wb + 49152, l1b, h1b, nullptr, nullptr, nullptr, nullptr, nullptr, Nn);
    gemm_mfma_k<4,192,64,true,false,false><<<gblk, 256, 0, stream>>>(
        h1b, xb, 128, wb + 57344, l2b, nullptr, h2, nullptr, nullptr, nullptr, nullptr, Nn);
    final_out_k<<<CDIV(Nn, 256), 256, 0, stream>>>(h2, ow, ob, out, Nn);
}

// Round 5
// 737.396 us; speedup vs baseline: 9.3329x; 1.1852x over previous
//
#include <hip/hip_runtime.h>
#include <math.h>

#define CDIV(a,b) (((a)+(b)-1)/(b))

typedef __attribute__((ext_vector_type(8))) short bfrag;
typedef __attribute__((ext_vector_type(4))) float ffrag;

__device__ inline unsigned short f2bf(float f) {
    unsigned int u = __float_as_uint(f);
    return (unsigned short)((u + 0x7fffu + ((u >> 16) & 1u)) >> 16);
}
__device__ inline float bf2f(unsigned short u) {
    return __uint_as_float(((unsigned int)u) << 16);
}
__device__ inline float sigf(float x) {
    return __builtin_amdgcn_rcpf(1.f + __expf(-x));
}
__device__ inline float tanhfast(float x) {
    float t = __expf(-2.f * fabsf(x));
    float r = (1.f - t) * __builtin_amdgcn_rcpf(1.f + t);
    return copysignf(r, x);
}
// swizzled element offset into a [32][128] bf16 LDS tile (16B-chunk XOR swizzle)
__device__ inline int hoff(int row, int k) {
    int sw = ((k >> 3) ^ row) & 15;
    return row * 128 + sw * 8 + (k & 7);
}

// ---------------------------------------------------------------- utils
__global__ void zero_i32(int* __restrict__ p, int n) {
    int i = blockIdx.x * 256 + threadIdx.x;
    if (i < n) p[i] = 0;
}
__global__ void init_score_k(float* __restrict__ sc, const float* __restrict__ b, int n) {
    int i = blockIdx.x * 256 + threadIdx.x;
    if (i < n) sc[i] = b[0];
}
__global__ void convert_bf_k(const float* __restrict__ src, unsigned short* __restrict__ dst, int n) {
    int i = blockIdx.x * 256 + threadIdx.x;
    if (i < n) dst[i] = f2bf(src[i]);
}

// ---------------------------------------------------------------- CSR build
__global__ void hist_k(const int* __restrict__ ei, int E, int ET, int* __restrict__ deg) {
    int e = blockIdx.x * 256 + threadIdx.x;
    if (e >= ET) return;
    int d = (e < E) ? ei[E + e] : e - E;
    atomicAdd(deg + d, 1);
}

__global__ __launch_bounds__(256)
void scan1_k(const int* __restrict__ deg, int* __restrict__ row_ptr,
             int* __restrict__ part, int Nn) {
    __shared__ int ls[256];
    int t = threadIdx.x;
    int base = blockIdx.x * 1024 + t * 4;
    int v[4];
    #pragma unroll
    for (int j = 0; j < 4; ++j) v[j] = (base + j < Nn) ? deg[base + j] : 0;
    int s = v[0] + v[1] + v[2] + v[3];
    ls[t] = s;
    __syncthreads();
    for (int off = 1; off < 256; off <<= 1) {
        int o = (t >= off) ? ls[t - off] : 0;
        __syncthreads();
        ls[t] += o;
        __syncthreads();
    }
    int run = ls[t] - s;
    if (t == 255) part[blockIdx.x] = ls[255];
    #pragma unroll
    for (int j = 0; j < 4; ++j) {
        if (base + j < Nn) row_ptr[base + j] = run;
        run += v[j];
    }
}
__global__ void scan2_k(int* __restrict__ part, int nb) {
    int lane = threadIdx.x;
    int v = (lane < nb) ? part[lane] : 0;
    int orig = v;
    for (int off = 1; off < 64; off <<= 1) {
        int o = __shfl_up(v, off);
        if (lane >= off) v += o;
    }
    if (lane < nb) part[lane] = v - orig;
}
__global__ void scan3_k(const int* __restrict__ part, int* __restrict__ row_ptr,
                        int* __restrict__ cursor, int Nn) {
    int i = blockIdx.x * 256 + threadIdx.x;
    if (i >= Nn) return;
    int v = row_ptr[i] + part[i >> 10];
    row_ptr[i] = v;
    cursor[i] = v;
}

__global__ void fill_k(const int* __restrict__ ei, int E, int ET,
                       int* __restrict__ cursor, int* __restrict__ csr_src) {
    int e = blockIdx.x * 256 + threadIdx.x;
    if (e >= ET) return;
    int s, d;
    if (e < E) { s = ei[e]; d = ei[E + e]; } else { s = e - E; d = s; }
    int pos = atomicAdd(cursor + d, 1);
    csr_src[pos] = s;
}

// ---------------------------------------------------------------- weight packs
__global__ void pack_w_k(const float* __restrict__ Wih, const float* __restrict__ Whh,
                         const float* __restrict__ bih, const float* __restrict__ bhh,
                         unsigned short* __restrict__ Wp, float* __restrict__ bsum) {
    int i = blockIdx.x * 256 + threadIdx.x;
    if (i < 1024) bsum[i] = bih[i] + bhh[i];
    if (i >= 2 * 512 * 256) return;
    int k = i & 255, j = (i >> 8) & 511, d = i >> 17;
    float v = (k < 128) ? Wih[((size_t)d * 512 + j) * 128 + k]
                        : Whh[((size_t)d * 512 + j) * 128 + (k - 128)];
    Wp[i] = f2bf(v);
}

__global__ void pack_wb_k(const float* __restrict__ W1, const float* __restrict__ Ws,
                          const float* __restrict__ l1w, const float* __restrict__ l2w,
                          unsigned short* __restrict__ wb) {
    int i = blockIdx.x * 256 + threadIdx.x;
    if (i >= 69632) return;
    float v;
    if (i < 16384)      v = W1[i];
    else if (i < 49152) v = Ws[i - 16384];
    else if (i < 57344) v = l1w[i - 49152];
    else                v = l2w[i - 57344];
    wb[i] = f2bf(v);
}

// ---------------------------------------------------------------- MFMA GEMM
template<int NT, int K, int K1, bool RELU, bool FUSE, bool BFOUT>
__global__ __launch_bounds__(256)
void gemm_mfma_k(const unsigned short* __restrict__ A1, const unsigned short* __restrict__ A2,
                 int ldA2, const unsigned short* __restrict__ Wb, const float* __restrict__ bias,
                 unsigned short* __restrict__ Cb, float* __restrict__ Cf,
                 const float* __restrict__ asl, const float* __restrict__ adl,
                 float* __restrict__ es, float* __restrict__ ed, int M)
{
    int tid = threadIdx.x;
    int wv = tid >> 6, lane = tid & 63;
    int col = lane & 15, kg = lane >> 4;
    int row0 = blockIdx.x * 64 + wv * 16;
    int mrow = row0 + col;
    bool mok = mrow < M;

    ffrag acc[NT];
    #pragma unroll
    for (int t = 0; t < NT; ++t) acc[t] = (ffrag){0.f, 0.f, 0.f, 0.f};

    #pragma unroll
    for (int ks = 0; ks < K / 32; ++ks) {
        int kk = ks * 32 + kg * 8;
        bfrag a = (bfrag){0,0,0,0,0,0,0,0};
        if (mok) {
            if (kk < K1) a = *(const bfrag*)(A1 + (size_t)mrow * K1 + kk);
            else         a = *(const bfrag*)(A2 + (size_t)mrow * ldA2 + (kk - K1));
        }
        #pragma unroll
        for (int t = 0; t < NT; ++t) {
            bfrag b = *(const bfrag*)(Wb + (size_t)(t * 16 + col) * K + kk);
            acc[t] = __builtin_amdgcn_mfma_f32_16x16x32_bf16(a, b, acc[t], 0, 0, 0);
        }
    }

    #pragma unroll
    for (int r = 0; r < 4; ++r) {
        int n = row0 + kg * 4 + r;
        bool ok = n < M;
        float e0 = 0.f, e1 = 0.f, d0 = 0.f, d1 = 0.f;
        #pragma unroll
        for (int t = 0; t < NT; ++t) {
            float v = acc[t][r];
            if (FUSE) {
                int ch = t * 16 + col;
                if (t < NT / 2) { e0 = fmaf(v, asl[ch], e0); d0 = fmaf(v, adl[ch], d0); }
                else            { e1 = fmaf(v, asl[ch], e1); d1 = fmaf(v, adl[ch], d1); }
            }
            if (bias) v += bias[t * 16 + col];
            if (RELU) v = fmaxf(v, 0.f);
            if (ok) {
                if (BFOUT) Cb[(size_t)n * (NT * 16) + t * 16 + col] = f2bf(v);
                else       Cf[(size_t)n * (NT * 16) + t * 16 + col] = v;
            }
        }
        if (FUSE) {
            #pragma unroll
            for (int mk = 1; mk < 16; mk <<= 1) {
                e0 += __shfl_xor(e0, mk); e1 += __shfl_xor(e1, mk);
                d0 += __shfl_xor(d0, mk); d1 += __shfl_xor(d1, mk);
            }
            if (col == 0 && ok) {
                es[n * 2] = e0; es[n * 2 + 1] = e1;
                ed[n * 2] = d0; ed[n * 2 + 1] = d1;
            }
        }
    }
}

// ---------------------------------------------------------------- GAT aggregate
__global__ __launch_bounds__(256)
void gat_agg_k(const int* __restrict__ csr_src, const int* __restrict__ row_ptr,
               const int* __restrict__ deg,
               const unsigned short* __restrict__ xpb, const float* __restrict__ es,
               const float* __restrict__ ed, const float* __restrict__ bias,
               unsigned short* __restrict__ out, int Nn, int relu)
{
    int wid = (blockIdx.x * 256 + threadIdx.x) >> 6;
    int lane = threadIdx.x & 63;
    if (wid >= Nn) return;
    int n = wid;
    int beg = row_ptr[n];
    int dn = deg[n];
    float2 edv = *(const float2*)(ed + n * 2);

    int   src_c = 0;
    float z0_c = 0.f, z1_c = 0.f;
    float m0 = -3e38f, m1 = -3e38f, s0 = 0.f, s1 = 0.f;
    for (int i = lane; i < dn; i += 64) {
        int s = csr_src[beg + i];
        float2 e2 = *(const float2*)(es + s * 2);
        float z0 = e2.x + edv.x; z0 = z0 > 0.f ? z0 : 0.2f * z0;
        float z1 = e2.y + edv.y; z1 = z1 > 0.f ? z1 : 0.2f * z1;
        if (i == lane) { src_c = s; z0_c = z0; z1_c = z1; }
        float nm0 = fmaxf(m0, z0);
        s0 = s0 * __expf(m0 - nm0) + __expf(z0 - nm0); m0 = nm0;
        float nm1 = fmaxf(m1, z1);
        s1 = s1 * __expf(m1 - nm1) + __expf(z1 - nm1); m1 = nm1;
    }
    #pragma unroll
    for (int off = 32; off; off >>= 1) {
        float om0 = __shfl_xor(m0, off), os0 = __shfl_xor(s0, off);
        float nm0 = fmaxf(m0, om0);
        s0 = s0 * __expf(m0 - nm0) + os0 * __expf(om0 - nm0); m0 = nm0;
        float om1 = __shfl_xor(m1, off), os1 = __shfl_xor(s1, off);
        float nm1 = fmaxf(m1, om1);
        s1 = s1 * __expf(m1 - nm1) + os1 * __expf(om1 - nm1); m1 = nm1;
    }
    float inv0 = 1.f / s0, inv1 = 1.f / s1;

    float acc0 = 0.f, acc1 = 0.f;
    if (dn <= 64) {
        for (int i = 0; i < dn; ++i) {
            int s = __shfl(src_c, i);
            float a0 = __expf(__shfl(z0_c, i) - m0) * inv0;
            float a1 = __expf(__shfl(z1_c, i) - m1) * inv1;
            float aw = (lane < 32) ? a0 : a1;
            unsigned int u = *(const unsigned int*)(xpb + (size_t)s * 128 + 2 * lane);
            acc0 = fmaf(bf2f((unsigned short)(u & 0xffff)), aw, acc0);
            acc1 = fmaf(bf2f((unsigned short)(u >> 16)), aw, acc1);
        }
    } else {
        for (int i = 0; i < dn; ++i) {
            int s = csr_src[beg + i];
            float2 e2 = *(const float2*)(es + s * 2);
            float z0 = e2.x + edv.x; z0 = z0 > 0.f ? z0 : 0.2f * z0;
            float z1 = e2.y + edv.y; z1 = z1 > 0.f ? z1 : 0.2f * z1;
            float a0 = __expf(z0 - m0) * inv0;
            float a1 = __expf(z1 - m1) * inv1;
            float aw = (lane < 32) ? a0 : a1;
            unsigned int u = *(const unsigned int*)(xpb + (size_t)s * 128 + 2 * lane);
            acc0 = fmaf(bf2f((unsigned short)(u & 0xffff)), aw, acc0);
            acc1 = fmaf(bf2f((unsigned short)(u >> 16)), aw, acc1);
        }
    }
    float2 bb = *(const float2*)(bias + 2 * lane);
    float v0 = acc0 + bb.x;
    float v1 = acc1 + bb.y;
    if (relu) { v0 = fmaxf(v0, 0.f); v1 = fmaxf(v1, 0.f); }
    unsigned int o = (unsigned int)f2bf(v0) | ((unsigned int)f2bf(v1) << 16);
    *(unsigned int*)(out + (size_t)n * 128 + 2 * lane) = o;
}

// ---------------------------------------------------------------- fused biLSTM (all 3 steps)
// grid (nb, 2): blockIdx.y = direction. Block: 32 nodes, 4 waves, 3 time steps.
// h state: double-buffered swizzled LDS tile; c state: registers. No global h/c.
__global__ __launch_bounds__(256)
void lstm_all_k(const unsigned short* __restrict__ X0, const unsigned short* __restrict__ X1,
                const unsigned short* __restrict__ X2,
                const unsigned short* __restrict__ WpB, const float* __restrict__ bsumB,
                const float* __restrict__ jkw, float* __restrict__ score, int Nn)
{
    __shared__ unsigned short h_lds[2][32 * 128];
    int dir = blockIdx.y;
    const unsigned short* Xs[3];
    Xs[0] = dir ? X2 : X0;
    Xs[1] = X1;
    Xs[2] = dir ? X0 : X2;
    const unsigned short* Wp = WpB + (size_t)dir * 512 * 256;
    const float* bsum = bsumB + dir * 512;
    const float* wsc = jkw + dir * 128;

    int tid = threadIdx.x;
    int wv = tid >> 6, lane = tid & 63;
    int col = lane & 15, kg = lane >> 4;
    int node0 = blockIdx.x * 32;

    float c[2][2][4] = {};

    for (int i = 0; i < 3; ++i) {
        int t = dir ? (2 - i) : i;
        const unsigned short* Xt = Xs[i];
        int rb = (i + 1) & 1;   // h from previous step
        int wbuf = i & 1;       // h for next step

        ffrag acc[2][8];
        #pragma unroll
        for (int a = 0; a < 2; ++a)
            #pragma unroll
            for (int m = 0; m < 8; ++m) acc[a][m] = (ffrag){0.f, 0.f, 0.f, 0.f};

        const unsigned short* Ar0 = Xt + (size_t)(node0 + col) * 128;
        const unsigned short* Ar1 = Xt + (size_t)(node0 + 16 + col) * 128;

        int nks = (i == 0) ? 4 : 8;
        for (int ks = 0; ks < nks; ++ks) {
            int kk = ks * 32 + kg * 8;
            bfrag a0, a1;
            if (kk < 128) {
                a0 = *(const bfrag*)(Ar0 + kk);
                a1 = *(const bfrag*)(Ar1 + kk);
            } else {
                int kh = kk - 128;
                a0 = *(const bfrag*)&h_lds[rb][hoff(col, kh)];
                a1 = *(const bfrag*)&h_lds[rb][hoff(col, kh) + 16 * 128];  // row 16+col: (row&15)=col
            }
            #pragma unroll
            for (int m = 0; m < 8; ++m) {
                int gj = 16 * (4 * m + wv) + col;
                bfrag b = *(const bfrag*)(Wp + (size_t)gj * 256 + kk);
                acc[0][m] = __builtin_amdgcn_mfma_f32_16x16x32_bf16(a0, b, acc[0][m], 0, 0, 0);
                acc[1][m] = __builtin_amdgcn_mfma_f32_16x16x32_bf16(a1, b, acc[1][m], 0, 0, 0);
            }
        }

        #pragma unroll
        for (int nt = 0; nt < 2; ++nt) {
            float part[4] = {0.f, 0.f, 0.f, 0.f};
            #pragma unroll
            for (int m = 0; m < 2; ++m) {
                int k = 16 * (4 * m + wv) + col;
                float bi = bsum[k], bff = bsum[128 + k], bg = bsum[256 + k], bo = bsum[384 + k];
                float wk = wsc[k];
                #pragma unroll
                for (int r = 0; r < 4; ++r) {
                    int nl = nt * 16 + kg * 4 + r;   // local node 0..31
                    float gi = acc[nt][m][r]     + bi;
                    float gf = acc[nt][m + 2][r] + bff;
                    float gg = acc[nt][m + 4][r] + bg;
                    float go = acc[nt][m + 6][r] + bo;
                    float si = sigf(gi);
                    float sf = sigf(gf);
                    float so = sigf(go);
                    float tg = tanhfast(gg);
                    float cn = sf * c[nt][m][r] + si * tg;
                    float hn = so * tanhfast(cn);
                    c[nt][m][r] = cn;
                    h_lds[wbuf][hoff(nl, k)] = f2bf(hn);
                    part[r] += hn * wk;
                }
            }
            #pragma unroll
            for (int r = 0; r < 4; ++r) {
                float v = part[r];
                #pragma unroll
                for (int mk = 1; mk < 16; mk <<= 1) v += __shfl_xor(v, mk);
                if (col == 0) {
                    int n = node0 + nt * 16 + kg * 4 + r;
                    if (n < Nn) atomicAdd(&score[(size_t)t * Nn + n], v);
                }
            }
        }
        __syncthreads();   // h_lds[wbuf] complete before next step reads it
    }
}

// ---------------------------------------------------------------- JK combine + head
__global__ void jk_combine_k(const float* __restrict__ score, const unsigned short* __restrict__ x0,
                             const unsigned short* __restrict__ x1, const unsigned short* __restrict__ x2,
                             unsigned short* __restrict__ jkb, int N_) {
    int gid = blockIdx.x * 256 + threadIdx.x;
    int n = gid >> 5;
    if (n >= N_) return;
    int c = (gid & 31) * 4;
    float s0 = score[n], s1 = score[N_ + n], s2 = score[2*N_ + n];
    float mx = fmaxf(s0, fmaxf(s1, s2));
    float e0 = __expf(s0 - mx), e1 = __expf(s1 - mx), e2 = __expf(s2 - mx);
    float inv = 1.f / (e0 + e1 + e2);
    float a0 = e0 * inv, a1 = e1 * inv, a2 = e2 * inv;
    size_t off = (size_t)n * 128 + c;
    ushort4 u0 = *(const ushort4*)(x0 + off);
    ushort4 u1 = *(const ushort4*)(x1 + off);
    ushort4 u2 = *(const ushort4*)(x2 + off);
    ushort4 o;
    o.x = f2bf(a0*bf2f(u0.x) + a1*bf2f(u1.x) + a2*bf2f(u2.x));
    o.y = f2bf(a0*bf2f(u0.y) + a1*bf2f(u1.y) + a2*bf2f(u2.y));
    o.z = f2bf(a0*bf2f(u0.z) + a1*bf2f(u1.z) + a2*bf2f(u2.z));
    o.w = f2bf(a0*bf2f(u0.w) + a1*bf2f(u1.w) + a2*bf2f(u2.w));
    *(ushort4*)(jkb + off) = o;
}

__global__ void final_out_k(const float* __restrict__ h2, const float* __restrict__ ow,
                            const float* __restrict__ ob, float* __restrict__ out, int N_) {
    int n = blockIdx.x * 256 + threadIdx.x;
    if (n >= N_) return;
    float l[6];
    #pragma unroll
    for (int j = 0; j < 6; ++j) l[j] = ob[j];
    for (int c = 0; c < 64; c += 4) {
        float4 h4 = *(const float4*)(h2 + (size_t)n * 64 + c);
        #pragma unroll
        for (int j = 0; j < 6; ++j) {
            l[j] += h4.x * ow[j*64 + c + 0] + h4.y * ow[j*64 + c + 1]
                  + h4.z * ow[j*64 + c + 2] + h4.w * ow[j*64 + c + 3];
        }
    }
    float mx = l[0];
    #pragma unroll
    for (int j = 1; j < 6; ++j) mx = fmaxf(mx, l[j]);
    float se = 0.f;
    #pragma unroll
    for (int j = 0; j < 6; ++j) se += __expf(l[j] - mx);
    float ls = logf(se) + mx;
    #pragma unroll
    for (int j = 0; j < 6; ++j) out[(size_t)n * 6 + j] = l[j] - ls;
}

// ---------------------------------------------------------------- launch
extern "C" void kernel_launch(void* const* d_in, const int* in_sizes, int n_in,
                              void* d_out, int out_size, void* d_ws, size_t ws_size,
                              hipStream_t stream) {
    const float* x   = (const float*)d_in[0];
    const int*   ei  = (const int*)d_in[1];
    const float* W1  = (const float*)d_in[2];
    const float* a1s = (const float*)d_in[3];
    const float* a1d = (const float*)d_in[4];
    const float* b1  = (const float*)d_in[5];
    const float* Ws  = (const float*)d_in[6];
    const float* ass = (const float*)d_in[7];
    const float* asd = (const float*)d_in[8];
    const float* bs  = (const float*)d_in[9];
    const float* Wih = (const float*)d_in[10];
    const float* Whh = (const float*)d_in[11];
    const float* bih = (const float*)d_in[12];
    const float* bhh = (const float*)d_in[13];
    const float* jkw = (const float*)d_in[14];
    const float* jkb_b = (const float*)d_in[15];
    const float* l1w = (const float*)d_in[16];
    const float* l1b = (const float*)d_in[17];
    const float* l2w = (const float*)d_in[18];
    const float* l2b = (const float*)d_in[19];
    const float* ow  = (const float*)d_in[20];
    const float* ob  = (const float*)d_in[21];
    float* out = (float*)d_out;

    int Nn = in_sizes[0] / 128;
    int E  = in_sizes[1] / 2;
    int ET = E + Nn;
    size_t Np = ((size_t)Nn + 31) & ~(size_t)31;
    size_t Fp = Np * 128;

    float* w = (float*)d_ws;
    float* es    = w;                    // [2Nn]
    float* ed    = es + 2*Nn;            // [2Nn]
    float* score = ed + 2*Nn;            // [3Nn]
    float* bsum  = score + 3*Nn;         // [1024]
    float* h2    = bsum + 1024;          // [Nn*64]
    unsigned short* xb   = (unsigned short*)(h2 + (size_t)Nn*64);  // [Fp]
    unsigned short* xpb  = xb + Fp;      // [Fp]; reused as jkb
    unsigned short* xsb0 = xpb + Fp;
    unsigned short* xsb1 = xsb0 + Fp;
    unsigned short* xsb2 = xsb1 + Fp;
    unsigned short* h1b  = xsb2 + Fp;    // [Fp] (only Nn*64 used)
    unsigned short* Wp   = h1b + Fp;     // [2*512*256]
    unsigned short* wb   = Wp + 2*512*256; // [69632]
    int* deg     = (int*)(wb + 69632);
    int* row_ptr = deg + Nn;
    int* cursor  = row_ptr + Nn;
    int* part    = cursor + Nn;          // [64]
    int* csr_src = part + 64;            // [ET]
    unsigned short* jkb = xpb;

    // ---- CSR by destination (edges identical for all 3 layers)
    int nb1 = CDIV(Nn, 1024);
    zero_i32<<<CDIV(Nn, 256), 256, 0, stream>>>(deg, Nn);
    hist_k<<<CDIV(ET, 256), 256, 0, stream>>>(ei, E, ET, deg);
    scan1_k<<<nb1, 256, 0, stream>>>(deg, row_ptr, part, Nn);
    scan2_k<<<1, 64, 0, stream>>>(part, nb1);
    scan3_k<<<CDIV(Nn, 256), 256, 0, stream>>>(part, row_ptr, cursor, Nn);
    fill_k<<<CDIV(ET, 256), 256, 0, stream>>>(ei, E, ET, cursor, csr_src);

    // ---- packs / converts
    pack_w_k<<<CDIV(2*512*256, 256), 256, 0, stream>>>(Wih, Whh, bih, bhh, Wp, bsum);
    pack_wb_k<<<CDIV(69632, 256), 256, 0, stream>>>(W1, Ws, l1w, l2w, wb);
    convert_bf_k<<<CDIV(Nn*128, 256), 256, 0, stream>>>(x, xb, Nn*128);

    unsigned short* xsb_arr[3] = {xsb0, xsb1, xsb2};
    int gblk = CDIV(Nn, 64);

    for (int l = 0; l < 3; ++l) {
        const float* asl = (l == 0) ? a1s : ass + (size_t)(l-1) * 128;
        const float* adl = (l == 0) ? a1d : asd + (size_t)(l-1) * 128;
        const float* bl  = (l == 0) ? b1  : bs  + (size_t)(l-1) * 128;
        const unsigned short* Ain = (l == 0) ? xb : xsb_arr[l-1];
        const unsigned short* Wbl = wb + (size_t)l * 16384;
        gemm_mfma_k<8,128,128,false,true,true><<<gblk, 256, 0, stream>>>(
            Ain, Ain, 128, Wbl, nullptr, xpb, nullptr, asl, adl, es, ed, Nn);
        gat_agg_k<<<CDIV(Nn, 4), 256, 0, stream>>>(csr_src, row_ptr, deg, xpb, es, ed, bl,
                                                   xsb_arr[l], Nn, l > 0);
    }

    init_score_k<<<CDIV(3*Nn, 256), 256, 0, stream>>>(score, jkb_b, 3*Nn);
    lstm_all_k<<<dim3(CDIV(Nn, 32), 2), 256, 0, stream>>>(xsb0, xsb1, xsb2, Wp, bsum, jkw, score, Nn);

    jk_combine_k<<<CDIV(Nn*32, 256), 256, 0, stream>>>(score, xsb0, xsb1, xsb2, jkb, Nn);
    gemm_mfma_k<4,128,128,true,false,true><<<gblk, 256, 0, stream>>>(
        jkb, jkb, 128, wb + 49152, l1b, h1b, nullptr, nullptr, nullptr, nullptr, nullptr, Nn);
    gemm_mfma_k<4,192,64,true,false,false><<<gblk, 256, 0, stream>>>(
        h1b, xb, 128, wb + 57344, l2b, nullptr, h2, nullptr, nullptr, nullptr, nullptr, Nn);
    final_out_k<<<CDIV(Nn, 256), 256, 0, stream>>>(h2, ow, ob, out, Nn);
}